// Round 2
// baseline (887.327 us; speedup 1.0000x reference)
//
#include <hip/hip_runtime.h>
#include <math.h>

// ---------------------------------------------------------------------------
// GATEncoder forward.
//  - ee rank-collapse: ee = efeat @ (eenc_w @ fold(We[l],ae[l])) kills the
//    [E,256]x[256,256] GEMMs.
//  - node GEMMs in bf16 MFMA (16x16x32), 128x128 tile, global_load_lds.
//  - k_ee: 8 lanes/edge; results scatter-written in CSR order via perm[] so
//    k_agg reads ee fully coalesced and the eid indirection disappears.
//  - k_agg: WAVE-per-node (4 nodes / 256-block), zero __syncthreads (wave-
//    synchronous LDS slab + explicit lgkmcnt waits), full-wave row gather
//    (64 lanes x ushort4 = whole 512B row per instr), full-wave LN.
//    Single-pass softmax (scores O(0.1): exp without max-sub is exact).
// ---------------------------------------------------------------------------

typedef __attribute__((ext_vector_type(8))) short bf16x8;
typedef __attribute__((ext_vector_type(4))) float f32x4;

__device__ __forceinline__ ushort f2b(float f) {
    unsigned u; __builtin_memcpy(&u, &f, 4);
    unsigned r = u + 0x7FFF + ((u >> 16) & 1);
    return (ushort)(r >> 16);
}
__device__ __forceinline__ float b2f(ushort u) {
    unsigned x = (unsigned)u << 16;
    float f; __builtin_memcpy(&f, &x, 4);
    return f;
}

// ---------------- CSR build ----------------
__global__ void k_deg(const int* __restrict__ dst, int* __restrict__ deg, int E) {
    int e = blockIdx.x * 256 + threadIdx.x;
    if (e < E) atomicAdd(&deg[dst[e]], 1);
}

__global__ void k_bsum(const int* __restrict__ deg, int* __restrict__ bsum, int n) {
    __shared__ int wsum[4];
    int tid = threadIdx.x;
    int idx = blockIdx.x * 1024 + tid * 4;
    int4 v = make_int4(0, 0, 0, 0);
    if (idx + 3 < n) v = *(const int4*)(deg + idx);
    else {
        if (idx + 0 < n) v.x = deg[idx + 0];
        if (idx + 1 < n) v.y = deg[idx + 1];
        if (idx + 2 < n) v.z = deg[idx + 2];
    }
    int s = v.x + v.y + v.z + v.w;
#pragma unroll
    for (int off = 32; off; off >>= 1) s += __shfl_down(s, off, 64);
    if ((tid & 63) == 0) wsum[tid >> 6] = s;
    __syncthreads();
    if (tid == 0) bsum[blockIdx.x] = wsum[0] + wsum[1] + wsum[2] + wsum[3];
}

__global__ void k_bscan(const int* __restrict__ bsum, int* __restrict__ boff,
                        int* __restrict__ rowp, int NB, int n) {
    int tid = threadIdx.x;  // 64
    int v = (tid < NB) ? bsum[tid] : 0;
    int sc = v;
#pragma unroll
    for (int off = 1; off < 64; off <<= 1) {
        int t = __shfl_up(sc, off, 64);
        if ((tid & 63) >= off) sc += t;
    }
    if (tid < NB) boff[tid] = sc - v;
    if (tid == 63) rowp[n] = sc;
}

__global__ void k_bwrite(const int* __restrict__ deg, const int* __restrict__ boff,
                         int* __restrict__ rowp, int* __restrict__ cursor, int n) {
    __shared__ int wsum[4];
    __shared__ int woff_sh[4];
    int tid = threadIdx.x;
    int lane = tid & 63, wid = tid >> 6;
    int idx = blockIdx.x * 1024 + tid * 4;
    int4 v = make_int4(0, 0, 0, 0);
    if (idx + 3 < n) v = *(const int4*)(deg + idx);
    else {
        if (idx + 0 < n) v.x = deg[idx + 0];
        if (idx + 1 < n) v.y = deg[idx + 1];
        if (idx + 2 < n) v.z = deg[idx + 2];
    }
    int sum4 = v.x + v.y + v.z + v.w;
    int sc = sum4;
#pragma unroll
    for (int off = 1; off < 64; off <<= 1) {
        int t = __shfl_up(sc, off, 64);
        if (lane >= off) sc += t;
    }
    if (lane == 63) wsum[wid] = sc;
    __syncthreads();
    if (tid < 4) {
        int o = 0;
        for (int w = 0; w < tid; w++) o += wsum[w];
        woff_sh[tid] = o;
    }
    __syncthreads();
    int ex = boff[blockIdx.x] + woff_sh[wid] + (sc - sum4);
    int p0 = ex, p1 = ex + v.x, p2 = p1 + v.y, p3 = p2 + v.z;
    if (idx + 0 < n) { rowp[idx + 0] = p0; cursor[idx + 0] = p0; }
    if (idx + 1 < n) { rowp[idx + 1] = p1; cursor[idx + 1] = p1; }
    if (idx + 2 < n) { rowp[idx + 2] = p2; cursor[idx + 2] = p2; }
    if (idx + 3 < n) { rowp[idx + 3] = p3; cursor[idx + 3] = p3; }
}

// perm[e] = pos (CSR slot), esrc[pos] = src[e]
__global__ void k_scatter(const int* __restrict__ dst, const int* __restrict__ src,
                          int* __restrict__ cursor, int* __restrict__ perm,
                          int* __restrict__ esrc, int E) {
    int e = blockIdx.x * 256 + threadIdx.x;
    if (e < E) {
        int pos = atomicAdd(&cursor[dst[e]], 1);
        perm[e] = pos;
        esrc[pos] = src[e];
    }
}

// ---------------- tiny weight folds ----------------
__global__ void k_ew(const float* __restrict__ We, const float* __restrict__ ae,
                     float* __restrict__ ew) {
    int t = blockIdx.x * 256 + threadIdx.x;  // 3072
    if (t >= 3072) return;
    int l = t >> 10, r = t & 1023;
    int k = r >> 2, h = r & 3;
    const float* w = We + (size_t)l * 65536 + (size_t)k * 256 + h * 64;
    const float* a = ae + l * 256 + h * 64;
    float s = 0.f;
    for (int d = 0; d < 64; d++) s += w[d] * a[d];
    ew[t] = s;
}

__global__ void k_eew(const float* __restrict__ eenc_w, const float* __restrict__ eenc_b,
                      const float* __restrict__ ew, float* __restrict__ eew2,
                      float* __restrict__ eeb) {
    int t = blockIdx.x * 256 + threadIdx.x;
    if (t < 768) {
        int j = t / 12, lh = t % 12;
        int l = lh >> 2, h = lh & 3;
        float s = 0.f;
        for (int k = 0; k < 256; k++) s += eenc_w[j * 256 + k] * ew[l * 1024 + k * 4 + h];
        eew2[j * 12 + lh] = s;
    } else if (t < 780) {
        int lh = t - 768;
        int l = lh >> 2, h = lh & 3;
        float s = 0.f;
        for (int k = 0; k < 256; k++) s += eenc_b[k] * ew[l * 1024 + k * 4 + h];
        eeb[lh] = s;
    }
}

// ---------------- per-edge ee, CSR-order scatter output ----------------
// 8 lanes/edge. Leaders (q==0, 8 lanes, consecutive e) load perm[e] coalesced
// and scatter the 16B result to its CSR slot for each layer.
__global__ __launch_bounds__(256) void k_ee(const float* __restrict__ efeat,
                                            const float* __restrict__ eew2,
                                            const float* __restrict__ eeb,
                                            const int* __restrict__ perm,
                                            float* __restrict__ ee_l,  // [3][E][4] CSR
                                            int E) {
    const int tid = threadIdx.x;
    const int lane = tid & 63;
    const int wave = tid >> 6;
    const int q = lane & 7;         // col slot within edge
    const int g8 = lane >> 3;       // edge within wave-pass

    float W[8][12];
#pragma unroll
    for (int u = 0; u < 4; u++)
#pragma unroll
        for (int t = 0; t < 12; t++) {
            W[u][t]     = eew2[(q * 4 + u) * 12 + t];
            W[u + 4][t] = eew2[(32 + q * 4 + u) * 12 + t];
        }
    float Bv[12];
#pragma unroll
    for (int t = 0; t < 12; t++) Bv[t] = eeb[t];

    const int base = blockIdx.x * 128 + wave * 32;
#pragma unroll
    for (int p = 0; p < 4; p++) {
        int e = base + p * 8 + g8;   // uniform within each 8-lane group
        if (e >= E) return;
        float4 v0 = *(const float4*)(efeat + (size_t)e * 64 + q * 4);
        float4 v1 = *(const float4*)(efeat + (size_t)e * 64 + 32 + q * 4);
        float acc[12];
#pragma unroll
        for (int t = 0; t < 12; t++)
            acc[t] = v0.x * W[0][t] + v0.y * W[1][t] + v0.z * W[2][t] + v0.w * W[3][t] +
                     v1.x * W[4][t] + v1.y * W[5][t] + v1.z * W[6][t] + v1.w * W[7][t];
#pragma unroll
        for (int m = 1; m < 8; m <<= 1)
#pragma unroll
            for (int t = 0; t < 12; t++) acc[t] += __shfl_xor(acc[t], m, 64);
        if (q == 0) {
            int pos = perm[e];
#pragma unroll
            for (int l = 0; l < 3; l++) {
                float4 o = make_float4(acc[l * 4 + 0] + Bv[l * 4 + 0],
                                       acc[l * 4 + 1] + Bv[l * 4 + 1],
                                       acc[l * 4 + 2] + Bv[l * 4 + 2],
                                       acc[l * 4 + 3] + Bv[l * 4 + 3]);
                *(float4*)(ee_l + (size_t)l * E * 4 + (size_t)pos * 4) = o;
            }
        }
    }
}

// ---------------- fused prep: h->bf16 + all weight transposes ----------------
__global__ void k_prep(const float* __restrict__ h, const float* __restrict__ enc_w,
                       const float* __restrict__ Wn, const float* __restrict__ out_w,
                       ushort* __restrict__ hb, ushort* __restrict__ encT,
                       ushort* __restrict__ WnT, ushort* __restrict__ outT, int n4) {
    int t = blockIdx.x * 256 + threadIdx.x;
    if (t < n4) {
        float4 v = *(const float4*)(h + (size_t)t * 4);
        ushort4 o;
        o.x = f2b(v.x); o.y = f2b(v.y); o.z = f2b(v.z); o.w = f2b(v.w);
        *(ushort4*)(hb + (size_t)t * 4) = o;
        return;
    }
    t -= n4;
    if (t < 32768) {
        int nn = t >> 7, k = t & 127;
        encT[t] = f2b(enc_w[k * 256 + nn]);
        return;
    }
    t -= 32768;
    if (t < 3 * 65536) {
        int l = t >> 16, r = t & 65535;
        int nn = r >> 8, k = r & 255;
        WnT[(size_t)l * 65536 + r] = f2b(Wn[(size_t)l * 65536 + k * 256 + nn]);
        return;
    }
    t -= 3 * 65536;
    if (t < 65536) {
        int nn = t >> 8, k = t & 255;
        outT[t] = f2b(out_w[k * 256 + nn]);
    }
}

// ---------------- bf16 MFMA GEMM: C[M,256] = A[M,K] @ BT[256,K]^T ----------------
template <int KTILES, bool BIAS, bool STORE_F32, bool STORE_BF16>
__global__ __launch_bounds__(256) void gemm_mfma(const ushort* __restrict__ A,
                                                 const ushort* __restrict__ BT,
                                                 const float* __restrict__ bias,
                                                 float* __restrict__ Cf,
                                                 ushort* __restrict__ Cb, int M) {
    constexpr int K = KTILES * 32;
    __shared__ __align__(16) ushort As[128 * 32];
    __shared__ __align__(16) ushort Bs[128 * 32];
    const int tid = threadIdx.x;
    const int wave = tid >> 6;
    const int lane = tid & 63;
    const int rowBase = blockIdx.x * 128;
    const int colBase = blockIdx.y * 128;
    const int sRow = lane >> 2;
    const int sCol = (lane & 3) * 8;
    const int c0 = wave * 2, c1 = wave * 2 + 1;

    const ushort* gA0 = A + (size_t)(rowBase + c0 * 16 + sRow) * K + sCol;
    const ushort* gA1 = A + (size_t)(rowBase + c1 * 16 + sRow) * K + sCol;
    const ushort* gB0 = BT + (size_t)(colBase + c0 * 16 + sRow) * K + sCol;
    const ushort* gB1 = BT + (size_t)(colBase + c1 * 16 + sRow) * K + sCol;
    ushort* lA0 = As + c0 * 512;
    ushort* lA1 = As + c1 * 512;
    ushort* lB0 = Bs + c0 * 512;
    ushort* lB1 = Bs + c1 * 512;

    f32x4 acc[4][4] = {};
    const int wr = (wave >> 1) * 64, wc = (wave & 1) * 64;
    const int ml = lane & 15, q = lane >> 4;

    for (int kt = 0; kt < KTILES; ++kt) {
        __builtin_amdgcn_global_load_lds(
            (const __attribute__((address_space(1))) unsigned*)(gA0 + kt * 32),
            (__attribute__((address_space(3))) unsigned*)lA0, 16, 0, 0);
        __builtin_amdgcn_global_load_lds(
            (const __attribute__((address_space(1))) unsigned*)(gA1 + kt * 32),
            (__attribute__((address_space(3))) unsigned*)lA1, 16, 0, 0);
        __builtin_amdgcn_global_load_lds(
            (const __attribute__((address_space(1))) unsigned*)(gB0 + kt * 32),
            (__attribute__((address_space(3))) unsigned*)lB0, 16, 0, 0);
        __builtin_amdgcn_global_load_lds(
            (const __attribute__((address_space(1))) unsigned*)(gB1 + kt * 32),
            (__attribute__((address_space(3))) unsigned*)lB1, 16, 0, 0);
        __syncthreads();
        bf16x8 af[4], bfr[4];
#pragma unroll
        for (int i = 0; i < 4; i++)
            af[i] = *(const bf16x8*)&As[(wr + i * 16 + ml) * 32 + q * 8];
#pragma unroll
        for (int j = 0; j < 4; j++)
            bfr[j] = *(const bf16x8*)&Bs[(wc + j * 16 + ml) * 32 + q * 8];
#pragma unroll
        for (int i = 0; i < 4; i++)
#pragma unroll
            for (int j = 0; j < 4; j++)
                acc[i][j] = __builtin_amdgcn_mfma_f32_16x16x32_bf16(af[i], bfr[j], acc[i][j],
                                                                    0, 0, 0);
        __syncthreads();
    }

#pragma unroll
    for (int j = 0; j < 4; j++) {
        const int col = colBase + wc + j * 16 + ml;
        const float bb = BIAS ? bias[col] : 0.f;
#pragma unroll
        for (int i = 0; i < 4; i++) {
#pragma unroll
            for (int r = 0; r < 4; r++) {
                const int row = rowBase + wr + i * 16 + q * 4 + r;
                if (row < M) {
                    float v = acc[i][j][r] + bb;
                    if (STORE_F32) Cf[(size_t)row * 256 + col] = v;
                    if (STORE_BF16) Cb[(size_t)row * 256 + col] = f2b(v);
                }
            }
        }
    }
}

// ---------------- el/er: wave-per-node head dots ----------------
__global__ __launch_bounds__(256) void k_elr(const ushort* __restrict__ feat,
                                             const float* __restrict__ al,
                                             const float* __restrict__ ar,
                                             float* __restrict__ el,
                                             float* __restrict__ er, int N) {
    int lane = threadIdx.x & 63;
    int n = blockIdx.x * 4 + (threadIdx.x >> 6);
    if (n >= N) return;
    ushort4 f4 = *(const ushort4*)&feat[(size_t)n * 256 + lane * 4];
    float4 a4 = *(const float4*)&al[lane * 4];
    float4 r4 = *(const float4*)&ar[lane * 4];
    float f0 = b2f(f4.x), f1 = b2f(f4.y), f2 = b2f(f4.z), f3 = b2f(f4.w);
    float va = f0 * a4.x + f1 * a4.y + f2 * a4.z + f3 * a4.w;
    float vr = f0 * r4.x + f1 * r4.y + f2 * r4.z + f3 * r4.w;
#pragma unroll
    for (int m = 1; m < 16; m <<= 1) {
        va += __shfl_xor(va, m, 64);
        vr += __shfl_xor(vr, m, 64);
    }
    if ((lane & 15) == 0) {
        int h = lane >> 4;
        el[n * 4 + h] = va;
        er[n * 4 + h] = vr;
    }
}

// ---------------- wave-per-node softmax + aggregate + relu + res + LN -----
// One wave per node, 4 nodes per 256-block. No __syncthreads: the score
// phase writes this wave's LDS slab; an explicit lgkmcnt(0) wait makes it
// visible to the same wave's gather reads (LDS ops are in-order per wave).
// Gather: 64 lanes x ushort4 = one whole 512B feat row per load instr;
// w/src broadcast via same-address LDS reads (conflict-free broadcast).
template <bool WRITE_X>
__global__ __launch_bounds__(256) void k_agg(const int* __restrict__ rowp,
                                             const int* __restrict__ esrc,
                                             const float* __restrict__ ee,  // [E][4] CSR
                                             const float* __restrict__ el,
                                             const float* __restrict__ er,
                                             const ushort* __restrict__ feat,
                                             float* __restrict__ x_io,
                                             ushort* __restrict__ xb,
                                             const float* __restrict__ g,
                                             const float* __restrict__ b, int N) {
    __shared__ float w_sh[4][64][4];
    __shared__ int s_sh[4][64];
    const int wv = threadIdx.x >> 6;
    const int lane = threadIdx.x & 63;
    const int n = blockIdx.x * 4 + wv;
    if (n >= N) return;
    const int start = rowp[n], end = rowp[n + 1];
    const int h = lane >> 4;  // head for my 4 cols (lane*4..lane*4+3)

    float4 e4 = *(const float4*)(er + (size_t)n * 4);
    float ern[4] = {e4.x, e4.y, e4.z, e4.w};
    float wsum[4] = {0.f, 0.f, 0.f, 0.f};
    float acc[4] = {0.f, 0.f, 0.f, 0.f};

    for (int cs = start; cs < end; cs += 64) {
        const int m = min(64, end - cs);
        if (lane < m) {
            int pos = cs + lane;
            int s = esrc[pos];
            s_sh[wv][lane] = s;
            float4 eev = *(const float4*)(ee + (size_t)pos * 4);   // coalesced
            float4 elv = *(const float4*)(el + (size_t)s * 4);     // gather
            float ea[4] = {eev.x, eev.y, eev.z, eev.w};
            float la[4] = {elv.x, elv.y, elv.z, elv.w};
#pragma unroll
            for (int hh = 0; hh < 4; hh++) {
                float sc = la[hh] + ern[hh] + ea[hh];
                sc = (sc > 0.f) ? sc : 0.2f * sc;
                float w = __expf(sc);  // scores O(0.1): no max-sub needed
                w_sh[wv][lane][hh] = w;
                wsum[hh] += w;
            }
        }
        // make this wave's LDS writes visible to its own reads (in-order LDS)
        asm volatile("s_waitcnt lgkmcnt(0)" ::: "memory");
        __builtin_amdgcn_sched_barrier(0);
        for (int j = 0; j < m; ++j) {
            int s = s_sh[wv][j];          // broadcast read
            float w = w_sh[wv][j][h];     // broadcast read (per-16-lane group)
            ushort4 p = *(const ushort4*)&feat[(size_t)s * 256 + lane * 4];
            acc[0] += w * b2f(p.x);
            acc[1] += w * b2f(p.y);
            acc[2] += w * b2f(p.z);
            acc[3] += w * b2f(p.w);
        }
        // reads done before next chunk overwrites the slab
        asm volatile("s_waitcnt lgkmcnt(0)" ::: "memory");
        __builtin_amdgcn_sched_barrier(0);
    }

    // per-head weight totals across the wave (inactive score lanes hold 0)
#pragma unroll
    for (int mm = 1; mm < 64; mm <<= 1)
#pragma unroll
        for (int hh = 0; hh < 4; hh++) wsum[hh] += __shfl_xor(wsum[hh], mm, 64);

    float inv = (end > start) ? 1.f / wsum[h] : 0.f;
    float4 xr = *(const float4*)&x_io[(size_t)n * 256 + lane * 4];
    float xra[4] = {xr.x, xr.y, xr.z, xr.w};
    float y[4];
    float s1 = 0.f, s2 = 0.f;
#pragma unroll
    for (int u = 0; u < 4; u++) {
        float v = fmaxf(acc[u] * inv, 0.f);
        y[u] = v + xra[u];
        s1 += y[u];
        s2 += y[u] * y[u];
    }
#pragma unroll
    for (int mm = 1; mm < 64; mm <<= 1) {
        s1 += __shfl_xor(s1, mm, 64);
        s2 += __shfl_xor(s2, mm, 64);
    }
    float mu = s1 * (1.f / 256.f);
    float var = s2 * (1.f / 256.f) - mu * mu;
    float rstd = rsqrtf(var + 1e-5f);
    float4 gv = *(const float4*)&g[lane * 4];
    float4 bv = *(const float4*)&b[lane * 4];
    float ga[4] = {gv.x, gv.y, gv.z, gv.w};
    float ba[4] = {bv.x, bv.y, bv.z, bv.w};
    float o[4];
    ushort4 ob;
#pragma unroll
    for (int u = 0; u < 4; u++) o[u] = (y[u] - mu) * rstd * ga[u] + ba[u];
    ob.x = f2b(o[0]); ob.y = f2b(o[1]); ob.z = f2b(o[2]); ob.w = f2b(o[3]);
    if (WRITE_X)
        *(float4*)&x_io[(size_t)n * 256 + lane * 4] = make_float4(o[0], o[1], o[2], o[3]);
    *(ushort4*)&xb[(size_t)n * 256 + lane * 4] = ob;
}

// ---------------------------------------------------------------------------
extern "C" void kernel_launch(void* const* d_in, const int* in_sizes, int n_in,
                              void* d_out, int out_size, void* d_ws, size_t ws_size,
                              hipStream_t stream) {
    const float* h      = (const float*)d_in[0];
    const float* efeat  = (const float*)d_in[1];
    const int*   src    = (const int*)d_in[2];
    const int*   dst    = (const int*)d_in[3];
    const float* enc_w  = (const float*)d_in[4];
    const float* enc_b  = (const float*)d_in[5];
    const float* eenc_w = (const float*)d_in[6];
    const float* eenc_b = (const float*)d_in[7];
    const float* Wn     = (const float*)d_in[8];
    const float* We     = (const float*)d_in[9];
    const float* al     = (const float*)d_in[10];
    const float* ar     = (const float*)d_in[11];
    const float* ae     = (const float*)d_in[12];
    const float* ln_g   = (const float*)d_in[13];
    const float* ln_b   = (const float*)d_in[14];
    const float* out_w  = (const float*)d_in[15];
    const float* out_b  = (const float*)d_in[16];

    const int N = in_sizes[0] / 128;  // 50000
    const int E = in_sizes[2];        // 800000
    const int Mpad = ((N + 127) / 128) * 128;
    const int NB = (N + 1023) / 1024;

    char* ws = (char*)d_ws;
    size_t off = 0;
    auto alloc = [&](size_t bytes) -> char* {
        char* p = ws + off;
        off += (bytes + 255) & ~(size_t)255;
        return p;
    };
    float*  X      = (float*)alloc((size_t)Mpad * 256 * 4);
    ushort* Xb     = (ushort*)alloc((size_t)Mpad * 256 * 2);
    ushort* F      = (ushort*)alloc((size_t)Mpad * 256 * 2);
    ushort* hb     = (ushort*)alloc((size_t)Mpad * 128 * 2);
    float*  el     = (float*)alloc((size_t)N * 4 * 4);
    float*  er     = (float*)alloc((size_t)N * 4 * 4);
    float*  ee_l   = (float*)alloc((size_t)E * 12 * 4);  // [3][E][4] CSR order
    int*    esrc   = (int*)alloc((size_t)E * 4);
    int*    perm   = (int*)alloc((size_t)E * 4);
    int*    deg    = (int*)alloc((size_t)N * 4);
    int*    rowp   = (int*)alloc((size_t)(N + 1) * 4);
    int*    cursor = (int*)alloc((size_t)N * 4);
    int*    bsum   = (int*)alloc(64 * 4);
    int*    boff   = (int*)alloc(64 * 4);
    float*  ew     = (float*)alloc(3072 * 4);
    float*  eew2   = (float*)alloc(768 * 4);
    float*  eeb    = (float*)alloc(64);
    ushort* encT   = (ushort*)alloc(256 * 128 * 2);
    ushort* WnT    = (ushort*)alloc(3 * 256 * 256 * 2);
    ushort* outT   = (ushort*)alloc(256 * 256 * 2);
    (void)ws_size; (void)n_in; (void)out_size;

    // CSR by dst
    hipMemsetAsync(deg, 0, (size_t)N * 4, stream);
    k_deg<<<(E + 255) / 256, 256, 0, stream>>>(dst, deg, E);
    k_bsum<<<NB, 256, 0, stream>>>(deg, bsum, N);
    k_bscan<<<1, 64, 0, stream>>>(bsum, boff, rowp, NB, N);
    k_bwrite<<<NB, 256, 0, stream>>>(deg, boff, rowp, cursor, N);
    k_scatter<<<(E + 255) / 256, 256, 0, stream>>>(dst, src, cursor, perm, esrc, E);

    // folded edge-score weights + per-edge ee (CSR-order output, all 3 layers)
    k_ew<<<12, 256, 0, stream>>>(We, ae, ew);
    k_eew<<<4, 256, 0, stream>>>(eenc_w, eenc_b, ew, eew2, eeb);
    k_ee<<<(E + 127) / 128, 256, 0, stream>>>(efeat, eew2, eeb, perm, ee_l, E);

    // bf16 conversions + weight transposes, one dispatch
    const int n4 = N * 128 / 4;
    k_prep<<<(n4 + 32768 + 4 * 65536 + 255) / 256, 256, 0, stream>>>(
        h, enc_w, Wn, out_w, hb, encT, WnT, outT, n4);

    dim3 gG(Mpad / 128, 2);
    gemm_mfma<4, true, true, true><<<gG, 256, 0, stream>>>(hb, encT, enc_b, X, Xb, N);

    for (int l = 0; l < 3; l++) {
        gemm_mfma<8, false, false, true><<<gG, 256, 0, stream>>>(
            Xb, WnT + (size_t)l * 65536, nullptr, nullptr, F, N);
        k_elr<<<(N + 3) / 4, 256, 0, stream>>>(F, al + l * 256, ar + l * 256, el, er, N);
        if (l < 2)
            k_agg<true><<<(N + 3) / 4, 256, 0, stream>>>(rowp, esrc,
                ee_l + (size_t)l * E * 4, el, er, F, X, Xb, ln_g + l * 256,
                ln_b + l * 256, N);
        else
            k_agg<false><<<(N + 3) / 4, 256, 0, stream>>>(rowp, esrc,
                ee_l + (size_t)l * E * 4, el, er, F, X, Xb, ln_g + l * 256,
                ln_b + l * 256, N);
    }
    gemm_mfma<8, true, true, false><<<gG, 256, 0, stream>>>(Xb, outT, out_b,
                                                            (float*)d_out, nullptr, N);
}

// Round 3
// 862.547 us; speedup vs baseline: 1.0287x; 1.0287x over previous
//
#include <hip/hip_runtime.h>
#include <math.h>

// ---------------------------------------------------------------------------
// GATEncoder forward.
//  - ee rank-collapse: ee = efeat @ (eenc_w @ fold(We[l],ae[l])) kills the
//    [E,256]x[256,256] GEMMs.
//  - node GEMMs in bf16 MFMA (16x16x32), 128x128 tile, global_load_lds.
//  - k_ee: CSR-position-major; e=eid[pos] gather of full 256B efeat rows
//    (4 fully-consumed lines, no amplification) + coalesced 16B writes at
//    pos. (R2 lesson: scattered 16B WRITES 2x-amplify; scattered row READS
//    are free.)
//  - k_agg: WAVE-per-node (4 nodes / 256-block), zero __syncthreads (wave-
//    synchronous LDS slab + explicit lgkmcnt waits), full-wave row gather
//    (64 lanes x ushort4 = whole 512B row per instr), full-wave LN.
//    Single-pass softmax (scores O(0.1): exp without max-sub is exact).
// ---------------------------------------------------------------------------

typedef __attribute__((ext_vector_type(8))) short bf16x8;
typedef __attribute__((ext_vector_type(4))) float f32x4;

__device__ __forceinline__ ushort f2b(float f) {
    unsigned u; __builtin_memcpy(&u, &f, 4);
    unsigned r = u + 0x7FFF + ((u >> 16) & 1);
    return (ushort)(r >> 16);
}
__device__ __forceinline__ float b2f(ushort u) {
    unsigned x = (unsigned)u << 16;
    float f; __builtin_memcpy(&f, &x, 4);
    return f;
}

// ---------------- CSR build ----------------
__global__ void k_deg(const int* __restrict__ dst, int* __restrict__ deg, int E) {
    int e = blockIdx.x * 256 + threadIdx.x;
    if (e < E) atomicAdd(&deg[dst[e]], 1);
}

__global__ void k_bsum(const int* __restrict__ deg, int* __restrict__ bsum, int n) {
    __shared__ int wsum[4];
    int tid = threadIdx.x;
    int idx = blockIdx.x * 1024 + tid * 4;
    int4 v = make_int4(0, 0, 0, 0);
    if (idx + 3 < n) v = *(const int4*)(deg + idx);
    else {
        if (idx + 0 < n) v.x = deg[idx + 0];
        if (idx + 1 < n) v.y = deg[idx + 1];
        if (idx + 2 < n) v.z = deg[idx + 2];
    }
    int s = v.x + v.y + v.z + v.w;
#pragma unroll
    for (int off = 32; off; off >>= 1) s += __shfl_down(s, off, 64);
    if ((tid & 63) == 0) wsum[tid >> 6] = s;
    __syncthreads();
    if (tid == 0) bsum[blockIdx.x] = wsum[0] + wsum[1] + wsum[2] + wsum[3];
}

__global__ void k_bscan(const int* __restrict__ bsum, int* __restrict__ boff,
                        int* __restrict__ rowp, int NB, int n) {
    int tid = threadIdx.x;  // 64
    int v = (tid < NB) ? bsum[tid] : 0;
    int sc = v;
#pragma unroll
    for (int off = 1; off < 64; off <<= 1) {
        int t = __shfl_up(sc, off, 64);
        if ((tid & 63) >= off) sc += t;
    }
    if (tid < NB) boff[tid] = sc - v;
    if (tid == 63) rowp[n] = sc;
}

__global__ void k_bwrite(const int* __restrict__ deg, const int* __restrict__ boff,
                         int* __restrict__ rowp, int* __restrict__ cursor, int n) {
    __shared__ int wsum[4];
    __shared__ int woff_sh[4];
    int tid = threadIdx.x;
    int lane = tid & 63, wid = tid >> 6;
    int idx = blockIdx.x * 1024 + tid * 4;
    int4 v = make_int4(0, 0, 0, 0);
    if (idx + 3 < n) v = *(const int4*)(deg + idx);
    else {
        if (idx + 0 < n) v.x = deg[idx + 0];
        if (idx + 1 < n) v.y = deg[idx + 1];
        if (idx + 2 < n) v.z = deg[idx + 2];
    }
    int sum4 = v.x + v.y + v.z + v.w;
    int sc = sum4;
#pragma unroll
    for (int off = 1; off < 64; off <<= 1) {
        int t = __shfl_up(sc, off, 64);
        if (lane >= off) sc += t;
    }
    if (lane == 63) wsum[wid] = sc;
    __syncthreads();
    if (tid < 4) {
        int o = 0;
        for (int w = 0; w < tid; w++) o += wsum[w];
        woff_sh[tid] = o;
    }
    __syncthreads();
    int ex = boff[blockIdx.x] + woff_sh[wid] + (sc - sum4);
    int p0 = ex, p1 = ex + v.x, p2 = p1 + v.y, p3 = p2 + v.z;
    if (idx + 0 < n) { rowp[idx + 0] = p0; cursor[idx + 0] = p0; }
    if (idx + 1 < n) { rowp[idx + 1] = p1; cursor[idx + 1] = p1; }
    if (idx + 2 < n) { rowp[idx + 2] = p2; cursor[idx + 2] = p2; }
    if (idx + 3 < n) { rowp[idx + 3] = p3; cursor[idx + 3] = p3; }
}

// eid[pos] = e, esrc[pos] = src[e]
__global__ void k_scatter(const int* __restrict__ dst, const int* __restrict__ src,
                          int* __restrict__ cursor, int* __restrict__ eid,
                          int* __restrict__ esrc, int E) {
    int e = blockIdx.x * 256 + threadIdx.x;
    if (e < E) {
        int pos = atomicAdd(&cursor[dst[e]], 1);
        eid[pos] = e;
        esrc[pos] = src[e];
    }
}

// ---------------- tiny weight folds ----------------
__global__ void k_ew(const float* __restrict__ We, const float* __restrict__ ae,
                     float* __restrict__ ew) {
    int t = blockIdx.x * 256 + threadIdx.x;  // 3072
    if (t >= 3072) return;
    int l = t >> 10, r = t & 1023;
    int k = r >> 2, h = r & 3;
    const float* w = We + (size_t)l * 65536 + (size_t)k * 256 + h * 64;
    const float* a = ae + l * 256 + h * 64;
    float s = 0.f;
    for (int d = 0; d < 64; d++) s += w[d] * a[d];
    ew[t] = s;
}

__global__ void k_eew(const float* __restrict__ eenc_w, const float* __restrict__ eenc_b,
                      const float* __restrict__ ew, float* __restrict__ eew2,
                      float* __restrict__ eeb) {
    int t = blockIdx.x * 256 + threadIdx.x;
    if (t < 768) {
        int j = t / 12, lh = t % 12;
        int l = lh >> 2, h = lh & 3;
        float s = 0.f;
        for (int k = 0; k < 256; k++) s += eenc_w[j * 256 + k] * ew[l * 1024 + k * 4 + h];
        eew2[j * 12 + lh] = s;
    } else if (t < 780) {
        int lh = t - 768;
        int l = lh >> 2, h = lh & 3;
        float s = 0.f;
        for (int k = 0; k < 256; k++) s += eenc_b[k] * ew[l * 1024 + k * 4 + h];
        eeb[lh] = s;
    }
}

// ---------------- per-edge ee, CSR-position-major ----------------
// 8 lanes/edge-slot. pos runs coalesced over CSR positions; e=eid[pos] is a
// broadcast load per 8-lane group; efeat row e read as two float4/lane
// (whole 256B row = 4 fully-consumed lines). Leaders (q==0) write 16B
// results at consecutive pos -> coalesced 128B per 8 leaders, x3 layers.
__global__ __launch_bounds__(256) void k_ee(const float* __restrict__ efeat,
                                            const float* __restrict__ eew2,
                                            const float* __restrict__ eeb,
                                            const int* __restrict__ eid,
                                            float* __restrict__ ee_l,  // [3][E][4] CSR
                                            int E) {
    const int tid = threadIdx.x;
    const int lane = tid & 63;
    const int wave = tid >> 6;
    const int q = lane & 7;         // col slot within edge
    const int g8 = lane >> 3;       // edge-slot within wave-pass

    float W[8][12];
#pragma unroll
    for (int u = 0; u < 4; u++)
#pragma unroll
        for (int t = 0; t < 12; t++) {
            W[u][t]     = eew2[(q * 4 + u) * 12 + t];
            W[u + 4][t] = eew2[(32 + q * 4 + u) * 12 + t];
        }
    float Bv[12];
#pragma unroll
    for (int t = 0; t < 12; t++) Bv[t] = eeb[t];

    const int base = blockIdx.x * 128 + wave * 32;
#pragma unroll
    for (int p = 0; p < 4; p++) {
        int pos = base + p * 8 + g8;   // uniform within each 8-lane group
        if (pos >= E) return;
        int e = eid[pos];              // broadcast within group
        float4 v0 = *(const float4*)(efeat + (size_t)e * 64 + q * 4);
        float4 v1 = *(const float4*)(efeat + (size_t)e * 64 + 32 + q * 4);
        float acc[12];
#pragma unroll
        for (int t = 0; t < 12; t++)
            acc[t] = v0.x * W[0][t] + v0.y * W[1][t] + v0.z * W[2][t] + v0.w * W[3][t] +
                     v1.x * W[4][t] + v1.y * W[5][t] + v1.z * W[6][t] + v1.w * W[7][t];
#pragma unroll
        for (int m = 1; m < 8; m <<= 1)
#pragma unroll
            for (int t = 0; t < 12; t++) acc[t] += __shfl_xor(acc[t], m, 64);
        if (q == 0) {
#pragma unroll
            for (int l = 0; l < 3; l++) {
                float4 o = make_float4(acc[l * 4 + 0] + Bv[l * 4 + 0],
                                       acc[l * 4 + 1] + Bv[l * 4 + 1],
                                       acc[l * 4 + 2] + Bv[l * 4 + 2],
                                       acc[l * 4 + 3] + Bv[l * 4 + 3]);
                *(float4*)(ee_l + (size_t)l * E * 4 + (size_t)pos * 4) = o;
            }
        }
    }
}

// ---------------- fused prep: h->bf16 + all weight transposes ----------------
__global__ void k_prep(const float* __restrict__ h, const float* __restrict__ enc_w,
                       const float* __restrict__ Wn, const float* __restrict__ out_w,
                       ushort* __restrict__ hb, ushort* __restrict__ encT,
                       ushort* __restrict__ WnT, ushort* __restrict__ outT, int n4) {
    int t = blockIdx.x * 256 + threadIdx.x;
    if (t < n4) {
        float4 v = *(const float4*)(h + (size_t)t * 4);
        ushort4 o;
        o.x = f2b(v.x); o.y = f2b(v.y); o.z = f2b(v.z); o.w = f2b(v.w);
        *(ushort4*)(hb + (size_t)t * 4) = o;
        return;
    }
    t -= n4;
    if (t < 32768) {
        int nn = t >> 7, k = t & 127;
        encT[t] = f2b(enc_w[k * 256 + nn]);
        return;
    }
    t -= 32768;
    if (t < 3 * 65536) {
        int l = t >> 16, r = t & 65535;
        int nn = r >> 8, k = r & 255;
        WnT[(size_t)l * 65536 + r] = f2b(Wn[(size_t)l * 65536 + k * 256 + nn]);
        return;
    }
    t -= 3 * 65536;
    if (t < 65536) {
        int nn = t >> 8, k = t & 255;
        outT[t] = f2b(out_w[k * 256 + nn]);
    }
}

// ---------------- bf16 MFMA GEMM: C[M,256] = A[M,K] @ BT[256,K]^T ----------------
template <int KTILES, bool BIAS, bool STORE_F32, bool STORE_BF16>
__global__ __launch_bounds__(256) void gemm_mfma(const ushort* __restrict__ A,
                                                 const ushort* __restrict__ BT,
                                                 const float* __restrict__ bias,
                                                 float* __restrict__ Cf,
                                                 ushort* __restrict__ Cb, int M) {
    constexpr int K = KTILES * 32;
    __shared__ __align__(16) ushort As[128 * 32];
    __shared__ __align__(16) ushort Bs[128 * 32];
    const int tid = threadIdx.x;
    const int wave = tid >> 6;
    const int lane = tid & 63;
    const int rowBase = blockIdx.x * 128;
    const int colBase = blockIdx.y * 128;
    const int sRow = lane >> 2;
    const int sCol = (lane & 3) * 8;
    const int c0 = wave * 2, c1 = wave * 2 + 1;

    const ushort* gA0 = A + (size_t)(rowBase + c0 * 16 + sRow) * K + sCol;
    const ushort* gA1 = A + (size_t)(rowBase + c1 * 16 + sRow) * K + sCol;
    const ushort* gB0 = BT + (size_t)(colBase + c0 * 16 + sRow) * K + sCol;
    const ushort* gB1 = BT + (size_t)(colBase + c1 * 16 + sRow) * K + sCol;
    ushort* lA0 = As + c0 * 512;
    ushort* lA1 = As + c1 * 512;
    ushort* lB0 = Bs + c0 * 512;
    ushort* lB1 = Bs + c1 * 512;

    f32x4 acc[4][4] = {};
    const int wr = (wave >> 1) * 64, wc = (wave & 1) * 64;
    const int ml = lane & 15, q = lane >> 4;

    for (int kt = 0; kt < KTILES; ++kt) {
        __builtin_amdgcn_global_load_lds(
            (const __attribute__((address_space(1))) unsigned*)(gA0 + kt * 32),
            (__attribute__((address_space(3))) unsigned*)lA0, 16, 0, 0);
        __builtin_amdgcn_global_load_lds(
            (const __attribute__((address_space(1))) unsigned*)(gA1 + kt * 32),
            (__attribute__((address_space(3))) unsigned*)lA1, 16, 0, 0);
        __builtin_amdgcn_global_load_lds(
            (const __attribute__((address_space(1))) unsigned*)(gB0 + kt * 32),
            (__attribute__((address_space(3))) unsigned*)lB0, 16, 0, 0);
        __builtin_amdgcn_global_load_lds(
            (const __attribute__((address_space(1))) unsigned*)(gB1 + kt * 32),
            (__attribute__((address_space(3))) unsigned*)lB1, 16, 0, 0);
        __syncthreads();
        bf16x8 af[4], bfr[4];
#pragma unroll
        for (int i = 0; i < 4; i++)
            af[i] = *(const bf16x8*)&As[(wr + i * 16 + ml) * 32 + q * 8];
#pragma unroll
        for (int j = 0; j < 4; j++)
            bfr[j] = *(const bf16x8*)&Bs[(wc + j * 16 + ml) * 32 + q * 8];
#pragma unroll
        for (int i = 0; i < 4; i++)
#pragma unroll
            for (int j = 0; j < 4; j++)
                acc[i][j] = __builtin_amdgcn_mfma_f32_16x16x32_bf16(af[i], bfr[j], acc[i][j],
                                                                    0, 0, 0);
        __syncthreads();
    }

#pragma unroll
    for (int j = 0; j < 4; j++) {
        const int col = colBase + wc + j * 16 + ml;
        const float bb = BIAS ? bias[col] : 0.f;
#pragma unroll
        for (int i = 0; i < 4; i++) {
#pragma unroll
            for (int r = 0; r < 4; r++) {
                const int row = rowBase + wr + i * 16 + q * 4 + r;
                if (row < M) {
                    float v = acc[i][j][r] + bb;
                    if (STORE_F32) Cf[(size_t)row * 256 + col] = v;
                    if (STORE_BF16) Cb[(size_t)row * 256 + col] = f2b(v);
                }
            }
        }
    }
}

// ---------------- el/er: wave-per-node head dots ----------------
__global__ __launch_bounds__(256) void k_elr(const ushort* __restrict__ feat,
                                             const float* __restrict__ al,
                                             const float* __restrict__ ar,
                                             float* __restrict__ el,
                                             float* __restrict__ er, int N) {
    int lane = threadIdx.x & 63;
    int n = blockIdx.x * 4 + (threadIdx.x >> 6);
    if (n >= N) return;
    ushort4 f4 = *(const ushort4*)&feat[(size_t)n * 256 + lane * 4];
    float4 a4 = *(const float4*)&al[lane * 4];
    float4 r4 = *(const float4*)&ar[lane * 4];
    float f0 = b2f(f4.x), f1 = b2f(f4.y), f2 = b2f(f4.z), f3 = b2f(f4.w);
    float va = f0 * a4.x + f1 * a4.y + f2 * a4.z + f3 * a4.w;
    float vr = f0 * r4.x + f1 * r4.y + f2 * r4.z + f3 * r4.w;
#pragma unroll
    for (int m = 1; m < 16; m <<= 1) {
        va += __shfl_xor(va, m, 64);
        vr += __shfl_xor(vr, m, 64);
    }
    if ((lane & 15) == 0) {
        int h = lane >> 4;
        el[n * 4 + h] = va;
        er[n * 4 + h] = vr;
    }
}

// ---------------- wave-per-node softmax + aggregate + relu + res + LN -----
// One wave per node, 4 nodes per 256-block. No __syncthreads: the score
// phase writes this wave's LDS slab; an explicit lgkmcnt(0) wait makes it
// visible to the same wave's gather reads (LDS ops are in-order per wave).
// Gather: 64 lanes x ushort4 = one whole 512B feat row per load instr;
// w/src broadcast via same-address LDS reads (conflict-free broadcast).
template <bool WRITE_X>
__global__ __launch_bounds__(256) void k_agg(const int* __restrict__ rowp,
                                             const int* __restrict__ esrc,
                                             const float* __restrict__ ee,  // [E][4] CSR
                                             const float* __restrict__ el,
                                             const float* __restrict__ er,
                                             const ushort* __restrict__ feat,
                                             float* __restrict__ x_io,
                                             ushort* __restrict__ xb,
                                             const float* __restrict__ g,
                                             const float* __restrict__ b, int N) {
    __shared__ float w_sh[4][64][4];
    __shared__ int s_sh[4][64];
    const int wv = threadIdx.x >> 6;
    const int lane = threadIdx.x & 63;
    const int n = blockIdx.x * 4 + wv;
    if (n >= N) return;
    const int start = rowp[n], end = rowp[n + 1];
    const int h = lane >> 4;  // head for my 4 cols (lane*4..lane*4+3)

    float4 e4 = *(const float4*)(er + (size_t)n * 4);
    float ern[4] = {e4.x, e4.y, e4.z, e4.w};
    float wsum[4] = {0.f, 0.f, 0.f, 0.f};
    float acc[4] = {0.f, 0.f, 0.f, 0.f};

    for (int cs = start; cs < end; cs += 64) {
        const int m = min(64, end - cs);
        if (lane < m) {
            int pos = cs + lane;
            int s = esrc[pos];
            s_sh[wv][lane] = s;
            float4 eev = *(const float4*)(ee + (size_t)pos * 4);   // coalesced
            float4 elv = *(const float4*)(el + (size_t)s * 4);     // gather
            float ea[4] = {eev.x, eev.y, eev.z, eev.w};
            float la[4] = {elv.x, elv.y, elv.z, elv.w};
#pragma unroll
            for (int hh = 0; hh < 4; hh++) {
                float sc = la[hh] + ern[hh] + ea[hh];
                sc = (sc > 0.f) ? sc : 0.2f * sc;
                float w = __expf(sc);  // scores O(0.1): no max-sub needed
                w_sh[wv][lane][hh] = w;
                wsum[hh] += w;
            }
        }
        // make this wave's LDS writes visible to its own reads (in-order LDS)
        asm volatile("s_waitcnt lgkmcnt(0)" ::: "memory");
        __builtin_amdgcn_sched_barrier(0);
        for (int j = 0; j < m; ++j) {
            int s = s_sh[wv][j];          // broadcast read
            float w = w_sh[wv][j][h];     // broadcast read (per-16-lane group)
            ushort4 p = *(const ushort4*)&feat[(size_t)s * 256 + lane * 4];
            acc[0] += w * b2f(p.x);
            acc[1] += w * b2f(p.y);
            acc[2] += w * b2f(p.z);
            acc[3] += w * b2f(p.w);
        }
        // reads done before next chunk overwrites the slab
        asm volatile("s_waitcnt lgkmcnt(0)" ::: "memory");
        __builtin_amdgcn_sched_barrier(0);
    }

    // per-head weight totals across the wave (inactive score lanes hold 0)
#pragma unroll
    for (int mm = 1; mm < 64; mm <<= 1)
#pragma unroll
        for (int hh = 0; hh < 4; hh++) wsum[hh] += __shfl_xor(wsum[hh], mm, 64);

    float inv = (end > start) ? 1.f / wsum[h] : 0.f;
    float4 xr = *(const float4*)&x_io[(size_t)n * 256 + lane * 4];
    float xra[4] = {xr.x, xr.y, xr.z, xr.w};
    float y[4];
    float s1 = 0.f, s2 = 0.f;
#pragma unroll
    for (int u = 0; u < 4; u++) {
        float v = fmaxf(acc[u] * inv, 0.f);
        y[u] = v + xra[u];
        s1 += y[u];
        s2 += y[u] * y[u];
    }
#pragma unroll
    for (int mm = 1; mm < 64; mm <<= 1) {
        s1 += __shfl_xor(s1, mm, 64);
        s2 += __shfl_xor(s2, mm, 64);
    }
    float mu = s1 * (1.f / 256.f);
    float var = s2 * (1.f / 256.f) - mu * mu;
    float rstd = rsqrtf(var + 1e-5f);
    float4 gv = *(const float4*)&g[lane * 4];
    float4 bv = *(const float4*)&b[lane * 4];
    float ga[4] = {gv.x, gv.y, gv.z, gv.w};
    float ba[4] = {bv.x, bv.y, bv.z, bv.w};
    float o[4];
    ushort4 ob;
#pragma unroll
    for (int u = 0; u < 4; u++) o[u] = (y[u] - mu) * rstd * ga[u] + ba[u];
    ob.x = f2b(o[0]); ob.y = f2b(o[1]); ob.z = f2b(o[2]); ob.w = f2b(o[3]);
    if (WRITE_X)
        *(float4*)&x_io[(size_t)n * 256 + lane * 4] = make_float4(o[0], o[1], o[2], o[3]);
    *(ushort4*)&xb[(size_t)n * 256 + lane * 4] = ob;
}

// ---------------------------------------------------------------------------
extern "C" void kernel_launch(void* const* d_in, const int* in_sizes, int n_in,
                              void* d_out, int out_size, void* d_ws, size_t ws_size,
                              hipStream_t stream) {
    const float* h      = (const float*)d_in[0];
    const float* efeat  = (const float*)d_in[1];
    const int*   src    = (const int*)d_in[2];
    const int*   dst    = (const int*)d_in[3];
    const float* enc_w  = (const float*)d_in[4];
    const float* enc_b  = (const float*)d_in[5];
    const float* eenc_w = (const float*)d_in[6];
    const float* eenc_b = (const float*)d_in[7];
    const float* Wn     = (const float*)d_in[8];
    const float* We     = (const float*)d_in[9];
    const float* al     = (const float*)d_in[10];
    const float* ar     = (const float*)d_in[11];
    const float* ae     = (const float*)d_in[12];
    const float* ln_g   = (const float*)d_in[13];
    const float* ln_b   = (const float*)d_in[14];
    const float* out_w  = (const float*)d_in[15];
    const float* out_b  = (const float*)d_in[16];

    const int N = in_sizes[0] / 128;  // 50000
    const int E = in_sizes[2];        // 800000
    const int Mpad = ((N + 127) / 128) * 128;
    const int NB = (N + 1023) / 1024;

    char* ws = (char*)d_ws;
    size_t off = 0;
    auto alloc = [&](size_t bytes) -> char* {
        char* p = ws + off;
        off += (bytes + 255) & ~(size_t)255;
        return p;
    };
    float*  X      = (float*)alloc((size_t)Mpad * 256 * 4);
    ushort* Xb     = (ushort*)alloc((size_t)Mpad * 256 * 2);
    ushort* F      = (ushort*)alloc((size_t)Mpad * 256 * 2);
    ushort* hb     = (ushort*)alloc((size_t)Mpad * 128 * 2);
    float*  el     = (float*)alloc((size_t)N * 4 * 4);
    float*  er     = (float*)alloc((size_t)N * 4 * 4);
    float*  ee_l   = (float*)alloc((size_t)E * 12 * 4);  // [3][E][4] CSR order
    int*    esrc   = (int*)alloc((size_t)E * 4);
    int*    eid    = (int*)alloc((size_t)E * 4);
    int*    deg    = (int*)alloc((size_t)N * 4);
    int*    rowp   = (int*)alloc((size_t)(N + 1) * 4);
    int*    cursor = (int*)alloc((size_t)N * 4);
    int*    bsum   = (int*)alloc(64 * 4);
    int*    boff   = (int*)alloc(64 * 4);
    float*  ew     = (float*)alloc(3072 * 4);
    float*  eew2   = (float*)alloc(768 * 4);
    float*  eeb    = (float*)alloc(64);
    ushort* encT   = (ushort*)alloc(256 * 128 * 2);
    ushort* WnT    = (ushort*)alloc(3 * 256 * 256 * 2);
    ushort* outT   = (ushort*)alloc(256 * 256 * 2);
    (void)ws_size; (void)n_in; (void)out_size;

    // CSR by dst
    hipMemsetAsync(deg, 0, (size_t)N * 4, stream);
    k_deg<<<(E + 255) / 256, 256, 0, stream>>>(dst, deg, E);
    k_bsum<<<NB, 256, 0, stream>>>(deg, bsum, N);
    k_bscan<<<1, 64, 0, stream>>>(bsum, boff, rowp, NB, N);
    k_bwrite<<<NB, 256, 0, stream>>>(deg, boff, rowp, cursor, N);
    k_scatter<<<(E + 255) / 256, 256, 0, stream>>>(dst, src, cursor, eid, esrc, E);

    // folded edge-score weights + per-edge ee (CSR-order output, all 3 layers)
    k_ew<<<12, 256, 0, stream>>>(We, ae, ew);
    k_eew<<<4, 256, 0, stream>>>(eenc_w, eenc_b, ew, eew2, eeb);
    k_ee<<<(E + 127) / 128, 256, 0, stream>>>(efeat, eew2, eeb, eid, ee_l, E);

    // bf16 conversions + weight transposes, one dispatch
    const int n4 = N * 128 / 4;
    k_prep<<<(n4 + 32768 + 4 * 65536 + 255) / 256, 256, 0, stream>>>(
        h, enc_w, Wn, out_w, hb, encT, WnT, outT, n4);

    dim3 gG(Mpad / 128, 2);
    gemm_mfma<4, true, true, true><<<gG, 256, 0, stream>>>(hb, encT, enc_b, X, Xb, N);

    for (int l = 0; l < 3; l++) {
        gemm_mfma<8, false, false, true><<<gG, 256, 0, stream>>>(
            Xb, WnT + (size_t)l * 65536, nullptr, nullptr, F, N);
        k_elr<<<(N + 3) / 4, 256, 0, stream>>>(F, al + l * 256, ar + l * 256, el, er, N);
        if (l < 2)
            k_agg<true><<<(N + 3) / 4, 256, 0, stream>>>(rowp, esrc,
                ee_l + (size_t)l * E * 4, el, er, F, X, Xb, ln_g + l * 256,
                ln_b + l * 256, N);
        else
            k_agg<false><<<(N + 3) / 4, 256, 0, stream>>>(rowp, esrc,
                ee_l + (size_t)l * E * 4, el, er, F, X, Xb, ln_g + l * 256,
                ln_b + l * 256, N);
    }
    gemm_mfma<8, true, true, false><<<gG, 256, 0, stream>>>(Xb, outT, out_b,
                                                            (float*)d_out, nullptr, N);
}

// Round 4
// 829.855 us; speedup vs baseline: 1.0693x; 1.0394x over previous
//
#include <hip/hip_runtime.h>
#include <math.h>

// ---------------------------------------------------------------------------
// GATEncoder forward.
//  - ee rank-collapse: ee = efeat @ (eenc_w @ fold(We[l],ae[l])) kills the
//    [E,256]x[256,256] GEMMs.
//  - node GEMMs in bf16 MFMA (16x16x32), 128x128 tile, global_load_lds.
//  - k_ee: CSR-position-major; e=eid[pos] gather of full 256B efeat rows
//    (4 fully-consumed lines, no amplification) + coalesced 16B writes.
//  - NO f32 X stream: residual is read from Xb (bf16, same values the GEMMs
//    consume); k_agg updates Xb in place. Saves ~300MB HBM traffic/run.
//  - k_agg: WAVE-per-node, zero __syncthreads, 2-rows-per-load gather
//    (u16x8 16B/lane: lanes 0-31 row j, 32-63 row j+1), shfl merge, LN on
//    duplicated halves. Single-pass softmax (scores O(0.1): exp exact).
// ---------------------------------------------------------------------------

typedef __attribute__((ext_vector_type(8))) short bf16x8;
typedef __attribute__((ext_vector_type(8))) unsigned short u16x8;
typedef __attribute__((ext_vector_type(4))) float f32x4;

__device__ __forceinline__ ushort f2b(float f) {
    unsigned u; __builtin_memcpy(&u, &f, 4);
    unsigned r = u + 0x7FFF + ((u >> 16) & 1);
    return (ushort)(r >> 16);
}
__device__ __forceinline__ float b2f(ushort u) {
    unsigned x = (unsigned)u << 16;
    float f; __builtin_memcpy(&f, &x, 4);
    return f;
}

// ---------------- CSR build ----------------
__global__ void k_deg(const int* __restrict__ dst, int* __restrict__ deg, int E) {
    int e = blockIdx.x * 256 + threadIdx.x;
    if (e < E) atomicAdd(&deg[dst[e]], 1);
}

__global__ void k_bsum(const int* __restrict__ deg, int* __restrict__ bsum, int n) {
    __shared__ int wsum[4];
    int tid = threadIdx.x;
    int idx = blockIdx.x * 1024 + tid * 4;
    int4 v = make_int4(0, 0, 0, 0);
    if (idx + 3 < n) v = *(const int4*)(deg + idx);
    else {
        if (idx + 0 < n) v.x = deg[idx + 0];
        if (idx + 1 < n) v.y = deg[idx + 1];
        if (idx + 2 < n) v.z = deg[idx + 2];
    }
    int s = v.x + v.y + v.z + v.w;
#pragma unroll
    for (int off = 32; off; off >>= 1) s += __shfl_down(s, off, 64);
    if ((tid & 63) == 0) wsum[tid >> 6] = s;
    __syncthreads();
    if (tid == 0) bsum[blockIdx.x] = wsum[0] + wsum[1] + wsum[2] + wsum[3];
}

__global__ void k_bscan(const int* __restrict__ bsum, int* __restrict__ boff,
                        int* __restrict__ rowp, int NB, int n) {
    int tid = threadIdx.x;  // 64
    int v = (tid < NB) ? bsum[tid] : 0;
    int sc = v;
#pragma unroll
    for (int off = 1; off < 64; off <<= 1) {
        int t = __shfl_up(sc, off, 64);
        if ((tid & 63) >= off) sc += t;
    }
    if (tid < NB) boff[tid] = sc - v;
    if (tid == 63) rowp[n] = sc;
}

__global__ void k_bwrite(const int* __restrict__ deg, const int* __restrict__ boff,
                         int* __restrict__ rowp, int* __restrict__ cursor, int n) {
    __shared__ int wsum[4];
    __shared__ int woff_sh[4];
    int tid = threadIdx.x;
    int lane = tid & 63, wid = tid >> 6;
    int idx = blockIdx.x * 1024 + tid * 4;
    int4 v = make_int4(0, 0, 0, 0);
    if (idx + 3 < n) v = *(const int4*)(deg + idx);
    else {
        if (idx + 0 < n) v.x = deg[idx + 0];
        if (idx + 1 < n) v.y = deg[idx + 1];
        if (idx + 2 < n) v.z = deg[idx + 2];
    }
    int sum4 = v.x + v.y + v.z + v.w;
    int sc = sum4;
#pragma unroll
    for (int off = 1; off < 64; off <<= 1) {
        int t = __shfl_up(sc, off, 64);
        if (lane >= off) sc += t;
    }
    if (lane == 63) wsum[wid] = sc;
    __syncthreads();
    if (tid < 4) {
        int o = 0;
        for (int w = 0; w < tid; w++) o += wsum[w];
        woff_sh[tid] = o;
    }
    __syncthreads();
    int ex = boff[blockIdx.x] + woff_sh[wid] + (sc - sum4);
    int p0 = ex, p1 = ex + v.x, p2 = p1 + v.y, p3 = p2 + v.z;
    if (idx + 0 < n) { rowp[idx + 0] = p0; cursor[idx + 0] = p0; }
    if (idx + 1 < n) { rowp[idx + 1] = p1; cursor[idx + 1] = p1; }
    if (idx + 2 < n) { rowp[idx + 2] = p2; cursor[idx + 2] = p2; }
    if (idx + 3 < n) { rowp[idx + 3] = p3; cursor[idx + 3] = p3; }
}

// eid[pos] = e, esrc[pos] = src[e]
__global__ void k_scatter(const int* __restrict__ dst, const int* __restrict__ src,
                          int* __restrict__ cursor, int* __restrict__ eid,
                          int* __restrict__ esrc, int E) {
    int e = blockIdx.x * 256 + threadIdx.x;
    if (e < E) {
        int pos = atomicAdd(&cursor[dst[e]], 1);
        eid[pos] = e;
        esrc[pos] = src[e];
    }
}

// ---------------- tiny weight folds ----------------
__global__ void k_ew(const float* __restrict__ We, const float* __restrict__ ae,
                     float* __restrict__ ew) {
    int t = blockIdx.x * 256 + threadIdx.x;  // 3072
    if (t >= 3072) return;
    int l = t >> 10, r = t & 1023;
    int k = r >> 2, h = r & 3;
    const float* w = We + (size_t)l * 65536 + (size_t)k * 256 + h * 64;
    const float* a = ae + l * 256 + h * 64;
    float s = 0.f;
    for (int d = 0; d < 64; d++) s += w[d] * a[d];
    ew[t] = s;
}

__global__ void k_eew(const float* __restrict__ eenc_w, const float* __restrict__ eenc_b,
                      const float* __restrict__ ew, float* __restrict__ eew2,
                      float* __restrict__ eeb) {
    int t = blockIdx.x * 256 + threadIdx.x;
    if (t < 768) {
        int j = t / 12, lh = t % 12;
        int l = lh >> 2, h = lh & 3;
        float s = 0.f;
        for (int k = 0; k < 256; k++) s += eenc_w[j * 256 + k] * ew[l * 1024 + k * 4 + h];
        eew2[j * 12 + lh] = s;
    } else if (t < 780) {
        int lh = t - 768;
        int l = lh >> 2, h = lh & 3;
        float s = 0.f;
        for (int k = 0; k < 256; k++) s += eenc_b[k] * ew[l * 1024 + k * 4 + h];
        eeb[lh] = s;
    }
}

// ---------------- per-edge ee, CSR-position-major ----------------
// 8 lanes/edge-slot. pos runs coalesced over CSR positions; e=eid[pos] is a
// broadcast load per 8-lane group; efeat row e read as two float4/lane
// (whole 256B row = 4 fully-consumed lines). Leaders (q==0) write 16B
// results at consecutive pos -> coalesced 128B per 8 leaders, x3 layers.
__global__ __launch_bounds__(256) void k_ee(const float* __restrict__ efeat,
                                            const float* __restrict__ eew2,
                                            const float* __restrict__ eeb,
                                            const int* __restrict__ eid,
                                            float* __restrict__ ee_l,  // [3][E][4] CSR
                                            int E) {
    const int tid = threadIdx.x;
    const int lane = tid & 63;
    const int wave = tid >> 6;
    const int q = lane & 7;         // col slot within edge
    const int g8 = lane >> 3;       // edge-slot within wave-pass

    float W[8][12];
#pragma unroll
    for (int u = 0; u < 4; u++)
#pragma unroll
        for (int t = 0; t < 12; t++) {
            W[u][t]     = eew2[(q * 4 + u) * 12 + t];
            W[u + 4][t] = eew2[(32 + q * 4 + u) * 12 + t];
        }
    float Bv[12];
#pragma unroll
    for (int t = 0; t < 12; t++) Bv[t] = eeb[t];

    const int base = blockIdx.x * 128 + wave * 32;
#pragma unroll
    for (int p = 0; p < 4; p++) {
        int pos = base + p * 8 + g8;   // uniform within each 8-lane group
        if (pos >= E) return;
        int e = eid[pos];              // broadcast within group
        float4 v0 = *(const float4*)(efeat + (size_t)e * 64 + q * 4);
        float4 v1 = *(const float4*)(efeat + (size_t)e * 64 + 32 + q * 4);
        float acc[12];
#pragma unroll
        for (int t = 0; t < 12; t++)
            acc[t] = v0.x * W[0][t] + v0.y * W[1][t] + v0.z * W[2][t] + v0.w * W[3][t] +
                     v1.x * W[4][t] + v1.y * W[5][t] + v1.z * W[6][t] + v1.w * W[7][t];
#pragma unroll
        for (int m = 1; m < 8; m <<= 1)
#pragma unroll
            for (int t = 0; t < 12; t++) acc[t] += __shfl_xor(acc[t], m, 64);
        if (q == 0) {
#pragma unroll
            for (int l = 0; l < 3; l++) {
                float4 o = make_float4(acc[l * 4 + 0] + Bv[l * 4 + 0],
                                       acc[l * 4 + 1] + Bv[l * 4 + 1],
                                       acc[l * 4 + 2] + Bv[l * 4 + 2],
                                       acc[l * 4 + 3] + Bv[l * 4 + 3]);
                *(float4*)(ee_l + (size_t)l * E * 4 + (size_t)pos * 4) = o;
            }
        }
    }
}

// ---------------- fused prep: h->bf16 + all weight transposes ----------------
__global__ void k_prep(const float* __restrict__ h, const float* __restrict__ enc_w,
                       const float* __restrict__ Wn, const float* __restrict__ out_w,
                       ushort* __restrict__ hb, ushort* __restrict__ encT,
                       ushort* __restrict__ WnT, ushort* __restrict__ outT, int n4) {
    int t = blockIdx.x * 256 + threadIdx.x;
    if (t < n4) {
        float4 v = *(const float4*)(h + (size_t)t * 4);
        ushort4 o;
        o.x = f2b(v.x); o.y = f2b(v.y); o.z = f2b(v.z); o.w = f2b(v.w);
        *(ushort4*)(hb + (size_t)t * 4) = o;
        return;
    }
    t -= n4;
    if (t < 32768) {
        int nn = t >> 7, k = t & 127;
        encT[t] = f2b(enc_w[k * 256 + nn]);
        return;
    }
    t -= 32768;
    if (t < 3 * 65536) {
        int l = t >> 16, r = t & 65535;
        int nn = r >> 8, k = r & 255;
        WnT[(size_t)l * 65536 + r] = f2b(Wn[(size_t)l * 65536 + k * 256 + nn]);
        return;
    }
    t -= 3 * 65536;
    if (t < 65536) {
        int nn = t >> 8, k = t & 255;
        outT[t] = f2b(out_w[k * 256 + nn]);
    }
}

// ---------------- bf16 MFMA GEMM: C[M,256] = A[M,K] @ BT[256,K]^T ----------------
template <int KTILES, bool BIAS, bool STORE_F32, bool STORE_BF16>
__global__ __launch_bounds__(256) void gemm_mfma(const ushort* __restrict__ A,
                                                 const ushort* __restrict__ BT,
                                                 const float* __restrict__ bias,
                                                 float* __restrict__ Cf,
                                                 ushort* __restrict__ Cb, int M) {
    constexpr int K = KTILES * 32;
    __shared__ __align__(16) ushort As[128 * 32];
    __shared__ __align__(16) ushort Bs[128 * 32];
    const int tid = threadIdx.x;
    const int wave = tid >> 6;
    const int lane = tid & 63;
    const int rowBase = blockIdx.x * 128;
    const int colBase = blockIdx.y * 128;
    const int sRow = lane >> 2;
    const int sCol = (lane & 3) * 8;
    const int c0 = wave * 2, c1 = wave * 2 + 1;

    const ushort* gA0 = A + (size_t)(rowBase + c0 * 16 + sRow) * K + sCol;
    const ushort* gA1 = A + (size_t)(rowBase + c1 * 16 + sRow) * K + sCol;
    const ushort* gB0 = BT + (size_t)(colBase + c0 * 16 + sRow) * K + sCol;
    const ushort* gB1 = BT + (size_t)(colBase + c1 * 16 + sRow) * K + sCol;
    ushort* lA0 = As + c0 * 512;
    ushort* lA1 = As + c1 * 512;
    ushort* lB0 = Bs + c0 * 512;
    ushort* lB1 = Bs + c1 * 512;

    f32x4 acc[4][4] = {};
    const int wr = (wave >> 1) * 64, wc = (wave & 1) * 64;
    const int ml = lane & 15, q = lane >> 4;

    for (int kt = 0; kt < KTILES; ++kt) {
        __builtin_amdgcn_global_load_lds(
            (const __attribute__((address_space(1))) unsigned*)(gA0 + kt * 32),
            (__attribute__((address_space(3))) unsigned*)lA0, 16, 0, 0);
        __builtin_amdgcn_global_load_lds(
            (const __attribute__((address_space(1))) unsigned*)(gA1 + kt * 32),
            (__attribute__((address_space(3))) unsigned*)lA1, 16, 0, 0);
        __builtin_amdgcn_global_load_lds(
            (const __attribute__((address_space(1))) unsigned*)(gB0 + kt * 32),
            (__attribute__((address_space(3))) unsigned*)lB0, 16, 0, 0);
        __builtin_amdgcn_global_load_lds(
            (const __attribute__((address_space(1))) unsigned*)(gB1 + kt * 32),
            (__attribute__((address_space(3))) unsigned*)lB1, 16, 0, 0);
        __syncthreads();
        bf16x8 af[4], bfr[4];
#pragma unroll
        for (int i = 0; i < 4; i++)
            af[i] = *(const bf16x8*)&As[(wr + i * 16 + ml) * 32 + q * 8];
#pragma unroll
        for (int j = 0; j < 4; j++)
            bfr[j] = *(const bf16x8*)&Bs[(wc + j * 16 + ml) * 32 + q * 8];
#pragma unroll
        for (int i = 0; i < 4; i++)
#pragma unroll
            for (int j = 0; j < 4; j++)
                acc[i][j] = __builtin_amdgcn_mfma_f32_16x16x32_bf16(af[i], bfr[j], acc[i][j],
                                                                    0, 0, 0);
        __syncthreads();
    }

#pragma unroll
    for (int j = 0; j < 4; j++) {
        const int col = colBase + wc + j * 16 + ml;
        const float bb = BIAS ? bias[col] : 0.f;
#pragma unroll
        for (int i = 0; i < 4; i++) {
#pragma unroll
            for (int r = 0; r < 4; r++) {
                const int row = rowBase + wr + i * 16 + q * 4 + r;
                if (row < M) {
                    float v = acc[i][j][r] + bb;
                    if (STORE_F32) Cf[(size_t)row * 256 + col] = v;
                    if (STORE_BF16) Cb[(size_t)row * 256 + col] = f2b(v);
                }
            }
        }
    }
}

// ---------------- el/er: wave-per-node head dots ----------------
__global__ __launch_bounds__(256) void k_elr(const ushort* __restrict__ feat,
                                             const float* __restrict__ al,
                                             const float* __restrict__ ar,
                                             float* __restrict__ el,
                                             float* __restrict__ er, int N) {
    int lane = threadIdx.x & 63;
    int n = blockIdx.x * 4 + (threadIdx.x >> 6);
    if (n >= N) return;
    ushort4 f4 = *(const ushort4*)&feat[(size_t)n * 256 + lane * 4];
    float4 a4 = *(const float4*)&al[lane * 4];
    float4 r4 = *(const float4*)&ar[lane * 4];
    float f0 = b2f(f4.x), f1 = b2f(f4.y), f2 = b2f(f4.z), f3 = b2f(f4.w);
    float va = f0 * a4.x + f1 * a4.y + f2 * a4.z + f3 * a4.w;
    float vr = f0 * r4.x + f1 * r4.y + f2 * r4.z + f3 * r4.w;
#pragma unroll
    for (int m = 1; m < 16; m <<= 1) {
        va += __shfl_xor(va, m, 64);
        vr += __shfl_xor(vr, m, 64);
    }
    if ((lane & 15) == 0) {
        int h = lane >> 4;
        el[n * 4 + h] = va;
        er[n * 4 + h] = vr;
    }
}

// ---------------- wave-per-node softmax + aggregate + relu + res + LN -----
// One wave per node, 4 nodes / 256-block, zero __syncthreads (wave-
// synchronous LDS slab + explicit lgkmcnt waits). Gather: u16x8 16B/lane,
// lanes 0-31 cover row j fully (512B), lanes 32-63 row j+1 -> one load
// instr = 2 complete rows. Halves merged via shfl_xor(32). Residual read
// from xb (bf16); LN output written to xb in place (no f32 X stream).
__global__ __launch_bounds__(256) void k_agg(const int* __restrict__ rowp,
                                             const int* __restrict__ esrc,
                                             const float* __restrict__ ee,  // [E][4] CSR
                                             const float* __restrict__ el,
                                             const float* __restrict__ er,
                                             const ushort* __restrict__ feat,
                                             ushort* __restrict__ xb,  // in/out
                                             const float* __restrict__ g,
                                             const float* __restrict__ b, int N) {
    __shared__ float w_sh[4][64][4];
    __shared__ int s_sh[4][64];
    const int wv = threadIdx.x >> 6;
    const int lane = threadIdx.x & 63;
    const int n = blockIdx.x * 4 + wv;
    if (n >= N) return;
    const int start = rowp[n], end = rowp[n + 1];
    const int half = lane >> 5;  // row parity
    const int c = lane & 31;     // col group: cols c*8..c*8+7
    const int h = c >> 3;        // head for my cols

    float4 e4 = *(const float4*)(er + (size_t)n * 4);
    float ern[4] = {e4.x, e4.y, e4.z, e4.w};
    float wsum[4] = {0.f, 0.f, 0.f, 0.f};
    float acc[8] = {0.f, 0.f, 0.f, 0.f, 0.f, 0.f, 0.f, 0.f};

    for (int cs = start; cs < end; cs += 64) {
        const int m = min(64, end - cs);
        if (lane < m) {
            int pos = cs + lane;
            int s = esrc[pos];
            s_sh[wv][lane] = s;
            float4 eev = *(const float4*)(ee + (size_t)pos * 4);   // coalesced
            float4 elv = *(const float4*)(el + (size_t)s * 4);     // gather
            float ea[4] = {eev.x, eev.y, eev.z, eev.w};
            float la[4] = {elv.x, elv.y, elv.z, elv.w};
#pragma unroll
            for (int hh = 0; hh < 4; hh++) {
                float sc = la[hh] + ern[hh] + ea[hh];
                sc = (sc > 0.f) ? sc : 0.2f * sc;
                float w = __expf(sc);  // scores O(0.1): no max-sub needed
                w_sh[wv][lane][hh] = w;
                wsum[hh] += w;
            }
        }
        // make this wave's LDS writes visible to its own reads (in-order LDS)
        asm volatile("s_waitcnt lgkmcnt(0)" ::: "memory");
        __builtin_amdgcn_sched_barrier(0);
        for (int j = half; j < m; j += 2) {
            int s = s_sh[wv][j];          // broadcast read (per half)
            float w = w_sh[wv][j][h];     // broadcast read (per 8-lane group)
            u16x8 p = *(const u16x8*)&feat[(size_t)s * 256 + c * 8];
#pragma unroll
            for (int u = 0; u < 8; u++) acc[u] += w * b2f((ushort)p[u]);
        }
        // reads done before next chunk overwrites the slab
        asm volatile("s_waitcnt lgkmcnt(0)" ::: "memory");
        __builtin_amdgcn_sched_barrier(0);
    }

    // merge row-parity halves (lane pairs with lane^32, same col group)
#pragma unroll
    for (int u = 0; u < 8; u++) acc[u] += __shfl_xor(acc[u], 32, 64);

    // per-head weight totals across the wave (inactive score lanes hold 0)
#pragma unroll
    for (int mm = 1; mm < 64; mm <<= 1)
#pragma unroll
        for (int hh = 0; hh < 4; hh++) wsum[hh] += __shfl_xor(wsum[hh], mm, 64);

    float inv = (end > start) ? 1.f / wsum[h] : 0.f;
    u16x8 xr = *(const u16x8*)&xb[(size_t)n * 256 + c * 8];  // bf16 residual
    float y[8];
    float s1 = 0.f, s2 = 0.f;
#pragma unroll
    for (int u = 0; u < 8; u++) {
        float v = fmaxf(acc[u] * inv, 0.f);
        y[u] = v + b2f((ushort)xr[u]);
        s1 += y[u];
        s2 += y[u] * y[u];
    }
    // both halves hold identical y -> 64-lane butterfly double-counts; /512
#pragma unroll
    for (int mm = 1; mm < 64; mm <<= 1) {
        s1 += __shfl_xor(s1, mm, 64);
        s2 += __shfl_xor(s2, mm, 64);
    }
    float mu = s1 * (1.f / 512.f);
    float var = s2 * (1.f / 512.f) - mu * mu;
    float rstd = rsqrtf(var + 1e-5f);
    float4 gv0 = *(const float4*)&g[c * 8];
    float4 gv1 = *(const float4*)&g[c * 8 + 4];
    float4 bv0 = *(const float4*)&b[c * 8];
    float4 bv1 = *(const float4*)&b[c * 8 + 4];
    float ga[8] = {gv0.x, gv0.y, gv0.z, gv0.w, gv1.x, gv1.y, gv1.z, gv1.w};
    float ba[8] = {bv0.x, bv0.y, bv0.z, bv0.w, bv1.x, bv1.y, bv1.z, bv1.w};
    u16x8 ob;
#pragma unroll
    for (int u = 0; u < 8; u++) ob[u] = f2b((y[u] - mu) * rstd * ga[u] + ba[u]);
    if (half == 0)
        *(u16x8*)&xb[(size_t)n * 256 + c * 8] = ob;
}

// ---------------------------------------------------------------------------
extern "C" void kernel_launch(void* const* d_in, const int* in_sizes, int n_in,
                              void* d_out, int out_size, void* d_ws, size_t ws_size,
                              hipStream_t stream) {
    const float* h      = (const float*)d_in[0];
    const float* efeat  = (const float*)d_in[1];
    const int*   src    = (const int*)d_in[2];
    const int*   dst    = (const int*)d_in[3];
    const float* enc_w  = (const float*)d_in[4];
    const float* enc_b  = (const float*)d_in[5];
    const float* eenc_w = (const float*)d_in[6];
    const float* eenc_b = (const float*)d_in[7];
    const float* Wn     = (const float*)d_in[8];
    const float* We     = (const float*)d_in[9];
    const float* al     = (const float*)d_in[10];
    const float* ar     = (const float*)d_in[11];
    const float* ae     = (const float*)d_in[12];
    const float* ln_g   = (const float*)d_in[13];
    const float* ln_b   = (const float*)d_in[14];
    const float* out_w  = (const float*)d_in[15];
    const float* out_b  = (const float*)d_in[16];

    const int N = in_sizes[0] / 128;  // 50000
    const int E = in_sizes[2];        // 800000
    const int Mpad = ((N + 127) / 128) * 128;
    const int NB = (N + 1023) / 1024;

    char* ws = (char*)d_ws;
    size_t off = 0;
    auto alloc = [&](size_t bytes) -> char* {
        char* p = ws + off;
        off += (bytes + 255) & ~(size_t)255;
        return p;
    };
    ushort* Xb     = (ushort*)alloc((size_t)Mpad * 256 * 2);
    ushort* F      = (ushort*)alloc((size_t)Mpad * 256 * 2);
    ushort* hb     = (ushort*)alloc((size_t)Mpad * 128 * 2);
    float*  el     = (float*)alloc((size_t)N * 4 * 4);
    float*  er     = (float*)alloc((size_t)N * 4 * 4);
    float*  ee_l   = (float*)alloc((size_t)E * 12 * 4);  // [3][E][4] CSR order
    int*    esrc   = (int*)alloc((size_t)E * 4);
    int*    eid    = (int*)alloc((size_t)E * 4);
    int*    deg    = (int*)alloc((size_t)N * 4);
    int*    rowp   = (int*)alloc((size_t)(N + 1) * 4);
    int*    cursor = (int*)alloc((size_t)N * 4);
    int*    bsum   = (int*)alloc(64 * 4);
    int*    boff   = (int*)alloc(64 * 4);
    float*  ew     = (float*)alloc(3072 * 4);
    float*  eew2   = (float*)alloc(768 * 4);
    float*  eeb    = (float*)alloc(64);
    ushort* encT   = (ushort*)alloc(256 * 128 * 2);
    ushort* WnT    = (ushort*)alloc(3 * 256 * 256 * 2);
    ushort* outT   = (ushort*)alloc(256 * 256 * 2);
    (void)ws_size; (void)n_in; (void)out_size;

    // CSR by dst
    hipMemsetAsync(deg, 0, (size_t)N * 4, stream);
    k_deg<<<(E + 255) / 256, 256, 0, stream>>>(dst, deg, E);
    k_bsum<<<NB, 256, 0, stream>>>(deg, bsum, N);
    k_bscan<<<1, 64, 0, stream>>>(bsum, boff, rowp, NB, N);
    k_bwrite<<<NB, 256, 0, stream>>>(deg, boff, rowp, cursor, N);
    k_scatter<<<(E + 255) / 256, 256, 0, stream>>>(dst, src, cursor, eid, esrc, E);

    // folded edge-score weights + per-edge ee (CSR-order output, all 3 layers)
    k_ew<<<12, 256, 0, stream>>>(We, ae, ew);
    k_eew<<<4, 256, 0, stream>>>(eenc_w, eenc_b, ew, eew2, eeb);
    k_ee<<<(E + 127) / 128, 256, 0, stream>>>(efeat, eew2, eeb, eid, ee_l, E);

    // bf16 conversions + weight transposes, one dispatch
    const int n4 = N * 128 / 4;
    k_prep<<<(n4 + 32768 + 4 * 65536 + 255) / 256, 256, 0, stream>>>(
        h, enc_w, Wn, out_w, hb, encT, WnT, outT, n4);

    dim3 gG(Mpad / 128, 2);
    // encoder: bf16 output only (residual lives in Xb)
    gemm_mfma<4, true, false, true><<<gG, 256, 0, stream>>>(hb, encT, enc_b,
                                                            nullptr, Xb, N);

    for (int l = 0; l < 3; l++) {
        gemm_mfma<8, false, false, true><<<gG, 256, 0, stream>>>(
            Xb, WnT + (size_t)l * 65536, nullptr, nullptr, F, N);
        k_elr<<<(N + 3) / 4, 256, 0, stream>>>(F, al + l * 256, ar + l * 256, el, er, N);
        k_agg<<<(N + 3) / 4, 256, 0, stream>>>(rowp, esrc, ee_l + (size_t)l * E * 4,
                                               el, er, F, Xb, ln_g + l * 256,
                                               ln_b + l * 256, N);
    }
    gemm_mfma<8, true, true, false><<<gG, 256, 0, stream>>>(Xb, outT, out_b,
                                                            (float*)d_out, nullptr, N);
}

// Round 6
// 811.101 us; speedup vs baseline: 1.0940x; 1.0231x over previous
//
#include <hip/hip_runtime.h>
#include <math.h>

// ---------------------------------------------------------------------------
// GATEncoder forward.
//  - ee rank-collapse: ee = efeat @ (eenc_w @ fold(We[l],ae[l])) kills the
//    [E,256]x[256,256] GEMMs. ee stored bf16 (scores O(0.1); err ~4e-4).
//  - node GEMMs in bf16 MFMA (16x16x32), 128x128 tile, global_load_lds.
//    el/er fused into the F-GEMM epilogue (each wave's acc = 64 rows x one
//    head; 4-round shfl_xor reduce; unique (row,head) writer, f32 acc).
//  - k_ee: CSR-position-major; coalesced eid load + shfl broadcast; full
//    256B efeat row gather (4 consumed lines); coalesced 8B bf16 writes.
//  - NO f32 X stream: residual read from Xb (bf16); k_agg updates in place.
//  - k_agg: WAVE-per-node, zero __syncthreads, 2-rows-per-load gather
//    (u16x8 16B/lane), shfl merge, LN on duplicated halves. Single-pass
//    softmax (scores O(0.1): exp without max-sub is exact).
// ---------------------------------------------------------------------------

typedef __attribute__((ext_vector_type(8))) short bf16x8;
typedef __attribute__((ext_vector_type(8))) unsigned short u16x8;
typedef __attribute__((ext_vector_type(4))) float f32x4;

__device__ __forceinline__ ushort f2b(float f) {
    unsigned u; __builtin_memcpy(&u, &f, 4);
    unsigned r = u + 0x7FFF + ((u >> 16) & 1);
    return (ushort)(r >> 16);
}
__device__ __forceinline__ float b2f(ushort u) {
    unsigned x = (unsigned)u << 16;
    float f; __builtin_memcpy(&f, &x, 4);
    return f;
}

// ---------------- CSR build ----------------
__global__ void k_deg(const int* __restrict__ dst, int* __restrict__ deg, int E) {
    int e = blockIdx.x * 256 + threadIdx.x;
    if (e < E) atomicAdd(&deg[dst[e]], 1);
}

__global__ void k_bsum(const int* __restrict__ deg, int* __restrict__ bsum, int n) {
    __shared__ int wsum[4];
    int tid = threadIdx.x;
    int idx = blockIdx.x * 1024 + tid * 4;
    int4 v = make_int4(0, 0, 0, 0);
    if (idx + 3 < n) v = *(const int4*)(deg + idx);
    else {
        if (idx + 0 < n) v.x = deg[idx + 0];
        if (idx + 1 < n) v.y = deg[idx + 1];
        if (idx + 2 < n) v.z = deg[idx + 2];
    }
    int s = v.x + v.y + v.z + v.w;
#pragma unroll
    for (int off = 32; off; off >>= 1) s += __shfl_down(s, off, 64);
    if ((tid & 63) == 0) wsum[tid >> 6] = s;
    __syncthreads();
    if (tid == 0) bsum[blockIdx.x] = wsum[0] + wsum[1] + wsum[2] + wsum[3];
}

__global__ void k_bscan(const int* __restrict__ bsum, int* __restrict__ boff,
                        int* __restrict__ rowp, int NB, int n) {
    int tid = threadIdx.x;  // 64
    int v = (tid < NB) ? bsum[tid] : 0;
    int sc = v;
#pragma unroll
    for (int off = 1; off < 64; off <<= 1) {
        int t = __shfl_up(sc, off, 64);
        if ((tid & 63) >= off) sc += t;
    }
    if (tid < NB) boff[tid] = sc - v;
    if (tid == 63) rowp[n] = sc;
}

__global__ void k_bwrite(const int* __restrict__ deg, const int* __restrict__ boff,
                         int* __restrict__ rowp, int* __restrict__ cursor, int n) {
    __shared__ int wsum[4];
    __shared__ int woff_sh[4];
    int tid = threadIdx.x;
    int lane = tid & 63, wid = tid >> 6;
    int idx = blockIdx.x * 1024 + tid * 4;
    int4 v = make_int4(0, 0, 0, 0);
    if (idx + 3 < n) v = *(const int4*)(deg + idx);
    else {
        if (idx + 0 < n) v.x = deg[idx + 0];
        if (idx + 1 < n) v.y = deg[idx + 1];
        if (idx + 2 < n) v.z = deg[idx + 2];
    }
    int sum4 = v.x + v.y + v.z + v.w;
    int sc = sum4;
#pragma unroll
    for (int off = 1; off < 64; off <<= 1) {
        int t = __shfl_up(sc, off, 64);
        if (lane >= off) sc += t;
    }
    if (lane == 63) wsum[wid] = sc;
    __syncthreads();
    if (tid < 4) {
        int o = 0;
        for (int w = 0; w < tid; w++) o += wsum[w];
        woff_sh[tid] = o;
    }
    __syncthreads();
    int ex = boff[blockIdx.x] + woff_sh[wid] + (sc - sum4);
    int p0 = ex, p1 = ex + v.x, p2 = p1 + v.y, p3 = p2 + v.z;
    if (idx + 0 < n) { rowp[idx + 0] = p0; cursor[idx + 0] = p0; }
    if (idx + 1 < n) { rowp[idx + 1] = p1; cursor[idx + 1] = p1; }
    if (idx + 2 < n) { rowp[idx + 2] = p2; cursor[idx + 2] = p2; }
    if (idx + 3 < n) { rowp[idx + 3] = p3; cursor[idx + 3] = p3; }
}

// eid[pos] = e, esrc[pos] = src[e]
__global__ void k_scatter(const int* __restrict__ dst, const int* __restrict__ src,
                          int* __restrict__ cursor, int* __restrict__ eid,
                          int* __restrict__ esrc, int E) {
    int e = blockIdx.x * 256 + threadIdx.x;
    if (e < E) {
        int pos = atomicAdd(&cursor[dst[e]], 1);
        eid[pos] = e;
        esrc[pos] = src[e];
    }
}

// ---------------- fused prep: h->bf16 + weight transposes + We*ae fold ------
__global__ void k_prep(const float* __restrict__ h, const float* __restrict__ enc_w,
                       const float* __restrict__ Wn, const float* __restrict__ out_w,
                       const float* __restrict__ We, const float* __restrict__ ae,
                       ushort* __restrict__ hb, ushort* __restrict__ encT,
                       ushort* __restrict__ WnT, ushort* __restrict__ outT,
                       float* __restrict__ ew, int n4) {
    int t = blockIdx.x * 256 + threadIdx.x;
    if (t < n4) {
        float4 v = *(const float4*)(h + (size_t)t * 4);
        ushort4 o;
        o.x = f2b(v.x); o.y = f2b(v.y); o.z = f2b(v.z); o.w = f2b(v.w);
        *(ushort4*)(hb + (size_t)t * 4) = o;
        return;
    }
    t -= n4;
    if (t < 32768) {
        int nn = t >> 7, k = t & 127;
        encT[t] = f2b(enc_w[k * 256 + nn]);
        return;
    }
    t -= 32768;
    if (t < 3 * 65536) {
        int l = t >> 16, r = t & 65535;
        int nn = r >> 8, k = r & 255;
        WnT[(size_t)l * 65536 + r] = f2b(Wn[(size_t)l * 65536 + k * 256 + nn]);
        return;
    }
    t -= 3 * 65536;
    if (t < 65536) {
        int nn = t >> 8, k = t & 255;
        outT[t] = f2b(out_w[k * 256 + nn]);
        return;
    }
    t -= 65536;
    if (t < 3072) {
        int l = t >> 10, r = t & 1023;
        int k = r >> 2, hh = r & 3;
        const float* w = We + (size_t)l * 65536 + (size_t)k * 256 + hh * 64;
        const float* a = ae + l * 256 + hh * 64;
        float s = 0.f;
        for (int d = 0; d < 64; d++) s += w[d] * a[d];
        ew[t] = s;
    }
}

__global__ void k_eew(const float* __restrict__ eenc_w, const float* __restrict__ eenc_b,
                      const float* __restrict__ ew, float* __restrict__ eew2,
                      float* __restrict__ eeb) {
    int t = blockIdx.x * 256 + threadIdx.x;
    if (t < 768) {
        int j = t / 12, lh = t % 12;
        int l = lh >> 2, h = lh & 3;
        float s = 0.f;
        for (int k = 0; k < 256; k++) s += eenc_w[j * 256 + k] * ew[l * 1024 + k * 4 + h];
        eew2[j * 12 + lh] = s;
    } else if (t < 780) {
        int lh = t - 768;
        int l = lh >> 2, h = lh & 3;
        float s = 0.f;
        for (int k = 0; k < 256; k++) s += eenc_b[k] * ew[l * 1024 + k * 4 + h];
        eeb[lh] = s;
    }
}

// ---------------- per-edge ee, CSR-position-major, bf16 out ----------------
// 8 lanes/edge-slot. eid loaded coalesced (one per lane) then shfl-broadcast;
// efeat row read as two float4/lane (whole 256B row). Leaders (q==0) write
// 8B bf16x4 at consecutive pos -> 64B per 8 leaders, x3 layers.
__global__ __launch_bounds__(256) void k_ee(const float* __restrict__ efeat,
                                            const float* __restrict__ eew2,
                                            const float* __restrict__ eeb,
                                            const int* __restrict__ eid,
                                            ushort* __restrict__ ee_l,  // [3][E][4] CSR
                                            int E) {
    const int tid = threadIdx.x;
    const int lane = tid & 63;
    const int wave = tid >> 6;
    const int q = lane & 7;         // col slot within edge
    const int g8 = lane >> 3;       // edge-slot within wave-pass

    float W[8][12];
#pragma unroll
    for (int u = 0; u < 4; u++)
#pragma unroll
        for (int t = 0; t < 12; t++) {
            W[u][t]     = eew2[(q * 4 + u) * 12 + t];
            W[u + 4][t] = eew2[(32 + q * 4 + u) * 12 + t];
        }
    float Bv[12];
#pragma unroll
    for (int t = 0; t < 12; t++) Bv[t] = eeb[t];

    const int base = blockIdx.x * 128 + wave * 32;
    // coalesced eid for this wave's 32 slots (lanes 0-31 hold them)
    int my_eid = 0;
    if (lane < 32 && base + lane < E) my_eid = eid[base + lane];
#pragma unroll
    for (int p = 0; p < 4; p++) {
        int pos = base + p * 8 + g8;   // uniform within each 8-lane group
        if (pos >= E) return;
        int e = __shfl(my_eid, p * 8 + g8, 64);
        float4 v0 = *(const float4*)(efeat + (size_t)e * 64 + q * 4);
        float4 v1 = *(const float4*)(efeat + (size_t)e * 64 + 32 + q * 4);
        float acc[12];
#pragma unroll
        for (int t = 0; t < 12; t++)
            acc[t] = v0.x * W[0][t] + v0.y * W[1][t] + v0.z * W[2][t] + v0.w * W[3][t] +
                     v1.x * W[4][t] + v1.y * W[5][t] + v1.z * W[6][t] + v1.w * W[7][t];
#pragma unroll
        for (int m = 1; m < 8; m <<= 1)
#pragma unroll
            for (int t = 0; t < 12; t++) acc[t] += __shfl_xor(acc[t], m, 64);
        if (q == 0) {
#pragma unroll
            for (int l = 0; l < 3; l++) {
                ushort4 o;
                o.x = f2b(acc[l * 4 + 0] + Bv[l * 4 + 0]);
                o.y = f2b(acc[l * 4 + 1] + Bv[l * 4 + 1]);
                o.z = f2b(acc[l * 4 + 2] + Bv[l * 4 + 2]);
                o.w = f2b(acc[l * 4 + 3] + Bv[l * 4 + 3]);
                *(ushort4*)(ee_l + (size_t)l * E * 4 + (size_t)pos * 4) = o;
            }
        }
    }
}

// ---------------- bf16 MFMA GEMM: C[M,256] = A[M,K] @ BT[256,K]^T ----------
// ELR: fused el/er epilogue. Each wave's acc covers 64 rows x 64 cols = one
// head (head=(colBase+wc)>>6); el[row,h]=sum_d acc*al[h*64+d] via 4 FMA +
// 4-round shfl_xor reduce (16-lane ml groups). Unique (row,head) writer.
template <int KTILES, bool BIAS, bool STORE_F32, bool STORE_BF16, bool ELR>
__global__ __launch_bounds__(256) void gemm_mfma(const ushort* __restrict__ A,
                                                 const ushort* __restrict__ BT,
                                                 const float* __restrict__ bias,
                                                 float* __restrict__ Cf,
                                                 ushort* __restrict__ Cb,
                                                 const float* __restrict__ al,
                                                 const float* __restrict__ ar,
                                                 float* __restrict__ el,
                                                 float* __restrict__ er, int M) {
    constexpr int K = KTILES * 32;
    __shared__ __align__(16) ushort As[128 * 32];
    __shared__ __align__(16) ushort Bs[128 * 32];
    const int tid = threadIdx.x;
    const int wave = tid >> 6;
    const int lane = tid & 63;
    const int rowBase = blockIdx.x * 128;
    const int colBase = blockIdx.y * 128;
    const int sRow = lane >> 2;
    const int sCol = (lane & 3) * 8;
    const int c0 = wave * 2, c1 = wave * 2 + 1;

    const ushort* gA0 = A + (size_t)(rowBase + c0 * 16 + sRow) * K + sCol;
    const ushort* gA1 = A + (size_t)(rowBase + c1 * 16 + sRow) * K + sCol;
    const ushort* gB0 = BT + (size_t)(colBase + c0 * 16 + sRow) * K + sCol;
    const ushort* gB1 = BT + (size_t)(colBase + c1 * 16 + sRow) * K + sCol;
    ushort* lA0 = As + c0 * 512;
    ushort* lA1 = As + c1 * 512;
    ushort* lB0 = Bs + c0 * 512;
    ushort* lB1 = Bs + c1 * 512;

    f32x4 acc[4][4] = {};
    const int wr = (wave >> 1) * 64, wc = (wave & 1) * 64;
    const int ml = lane & 15, q = lane >> 4;

    for (int kt = 0; kt < KTILES; ++kt) {
        __builtin_amdgcn_global_load_lds(
            (const __attribute__((address_space(1))) unsigned*)(gA0 + kt * 32),
            (__attribute__((address_space(3))) unsigned*)lA0, 16, 0, 0);
        __builtin_amdgcn_global_load_lds(
            (const __attribute__((address_space(1))) unsigned*)(gA1 + kt * 32),
            (__attribute__((address_space(3))) unsigned*)lA1, 16, 0, 0);
        __builtin_amdgcn_global_load_lds(
            (const __attribute__((address_space(1))) unsigned*)(gB0 + kt * 32),
            (__attribute__((address_space(3))) unsigned*)lB0, 16, 0, 0);
        __builtin_amdgcn_global_load_lds(
            (const __attribute__((address_space(1))) unsigned*)(gB1 + kt * 32),
            (__attribute__((address_space(3))) unsigned*)lB1, 16, 0, 0);
        __syncthreads();
        bf16x8 af[4], bfr[4];
#pragma unroll
        for (int i = 0; i < 4; i++)
            af[i] = *(const bf16x8*)&As[(wr + i * 16 + ml) * 32 + q * 8];
#pragma unroll
        for (int j = 0; j < 4; j++)
            bfr[j] = *(const bf16x8*)&Bs[(wc + j * 16 + ml) * 32 + q * 8];
#pragma unroll
        for (int i = 0; i < 4; i++)
#pragma unroll
            for (int j = 0; j < 4; j++)
                acc[i][j] = __builtin_amdgcn_mfma_f32_16x16x32_bf16(af[i], bfr[j], acc[i][j],
                                                                    0, 0, 0);
        __syncthreads();
    }

#pragma unroll
    for (int j = 0; j < 4; j++) {
        const int col = colBase + wc + j * 16 + ml;
        const float bb = BIAS ? bias[col] : 0.f;
#pragma unroll
        for (int i = 0; i < 4; i++) {
#pragma unroll
            for (int r = 0; r < 4; r++) {
                const int row = rowBase + wr + i * 16 + q * 4 + r;
                if (row < M) {
                    float v = acc[i][j][r] + bb;
                    if (STORE_F32) Cf[(size_t)row * 256 + col] = v;
                    if (STORE_BF16) Cb[(size_t)row * 256 + col] = f2b(v);
                }
            }
        }
    }

    if (ELR) {
        const int hh = (colBase + wc) >> 6;  // this wave's head
        float alv[4], arv[4];
#pragma unroll
        for (int j = 0; j < 4; j++) {
            alv[j] = al[hh * 64 + j * 16 + ml];
            arv[j] = ar[hh * 64 + j * 16 + ml];
        }
#pragma unroll
        for (int i = 0; i < 4; i++) {
#pragma unroll
            for (int r = 0; r < 4; r++) {
                float pe = acc[i][0][r] * alv[0] + acc[i][1][r] * alv[1] +
                           acc[i][2][r] * alv[2] + acc[i][3][r] * alv[3];
                float pr = acc[i][0][r] * arv[0] + acc[i][1][r] * arv[1] +
                           acc[i][2][r] * arv[2] + acc[i][3][r] * arv[3];
#pragma unroll
                for (int mm = 1; mm < 16; mm <<= 1) {
                    pe += __shfl_xor(pe, mm, 64);
                    pr += __shfl_xor(pr, mm, 64);
                }
                if (ml == 0) {
                    const int row = rowBase + wr + i * 16 + q * 4 + r;
                    if (row < M) {
                        el[(size_t)row * 4 + hh] = pe;
                        er[(size_t)row * 4 + hh] = pr;
                    }
                }
            }
        }
    }
}

// ---------------- wave-per-node softmax + aggregate + relu + res + LN -----
// One wave per node, 4 nodes / 256-block, zero __syncthreads (wave-
// synchronous LDS slab + explicit lgkmcnt waits). Gather: u16x8 16B/lane,
// lanes 0-31 cover row j fully (512B), lanes 32-63 row j+1 -> one load
// instr = 2 complete rows. Halves merged via shfl_xor(32). Residual read
// from xb (bf16); LN output written to xb in place (no f32 X stream).
__global__ __launch_bounds__(256) void k_agg(const int* __restrict__ rowp,
                                             const int* __restrict__ esrc,
                                             const ushort* __restrict__ ee,  // [E][4] bf16
                                             const float* __restrict__ el,
                                             const float* __restrict__ er,
                                             const ushort* __restrict__ feat,
                                             ushort* __restrict__ xb,  // in/out
                                             const float* __restrict__ g,
                                             const float* __restrict__ b, int N) {
    __shared__ float w_sh[4][64][4];
    __shared__ int s_sh[4][64];
    const int wv = threadIdx.x >> 6;
    const int lane = threadIdx.x & 63;
    const int n = blockIdx.x * 4 + wv;
    if (n >= N) return;
    const int start = rowp[n], end = rowp[n + 1];
    const int half = lane >> 5;  // row parity
    const int c = lane & 31;     // col group: cols c*8..c*8+7
    const int h = c >> 3;        // head for my cols

    float4 e4 = *(const float4*)(er + (size_t)n * 4);
    float ern[4] = {e4.x, e4.y, e4.z, e4.w};
    float wsum[4] = {0.f, 0.f, 0.f, 0.f};
    float acc[8] = {0.f, 0.f, 0.f, 0.f, 0.f, 0.f, 0.f, 0.f};

    for (int cs = start; cs < end; cs += 64) {
        const int m = min(64, end - cs);
        if (lane < m) {
            int pos = cs + lane;
            int s = esrc[pos];
            s_sh[wv][lane] = s;
            ushort4 eev = *(const ushort4*)(ee + (size_t)pos * 4);  // coalesced 8B
            float4 elv = *(const float4*)(el + (size_t)s * 4);      // gather
            float ea[4] = {b2f(eev.x), b2f(eev.y), b2f(eev.z), b2f(eev.w)};
            float la[4] = {elv.x, elv.y, elv.z, elv.w};
#pragma unroll
            for (int hh = 0; hh < 4; hh++) {
                float sc = la[hh] + ern[hh] + ea[hh];
                sc = (sc > 0.f) ? sc : 0.2f * sc;
                float w = __expf(sc);  // scores O(0.1): no max-sub needed
                w_sh[wv][lane][hh] = w;
                wsum[hh] += w;
            }
        }
        // make this wave's LDS writes visible to its own reads (in-order LDS)
        asm volatile("s_waitcnt lgkmcnt(0)" ::: "memory");
        __builtin_amdgcn_sched_barrier(0);
        for (int j = half; j < m; j += 2) {
            int s = s_sh[wv][j];          // broadcast read (per half)
            float w = w_sh[wv][j][h];     // broadcast read (per 8-lane group)
            u16x8 p = *(const u16x8*)&feat[(size_t)s * 256 + c * 8];
#pragma unroll
            for (int u = 0; u < 8; u++) acc[u] += w * b2f((ushort)p[u]);
        }
        // reads done before next chunk overwrites the slab
        asm volatile("s_waitcnt lgkmcnt(0)" ::: "memory");
        __builtin_amdgcn_sched_barrier(0);
    }

    // merge row-parity halves (lane pairs with lane^32, same col group)
#pragma unroll
    for (int u = 0; u < 8; u++) acc[u] += __shfl_xor(acc[u], 32, 64);

    // per-head weight totals across the wave (inactive score lanes hold 0)
#pragma unroll
    for (int mm = 1; mm < 64; mm <<= 1)
#pragma unroll
        for (int hh = 0; hh < 4; hh++) wsum[hh] += __shfl_xor(wsum[hh], mm, 64);

    float inv = (end > start) ? 1.f / wsum[h] : 0.f;
    u16x8 xr = *(const u16x8*)&xb[(size_t)n * 256 + c * 8];  // bf16 residual
    float y[8];
    float s1 = 0.f, s2 = 0.f;
#pragma unroll
    for (int u = 0; u < 8; u++) {
        float v = fmaxf(acc[u] * inv, 0.f);
        y[u] = v + b2f((ushort)xr[u]);
        s1 += y[u];
        s2 += y[u] * y[u];
    }
    // both halves hold identical y -> 64-lane butterfly double-counts; /512
#pragma unroll
    for (int mm = 1; mm < 64; mm <<= 1) {
        s1 += __shfl_xor(s1, mm, 64);
        s2 += __shfl_xor(s2, mm, 64);
    }
    float mu = s1 * (1.f / 512.f);
    float var = s2 * (1.f / 512.f) - mu * mu;
    float rstd = rsqrtf(var + 1e-5f);
    float4 gv0 = *(const float4*)&g[c * 8];
    float4 gv1 = *(const float4*)&g[c * 8 + 4];
    float4 bv0 = *(const float4*)&b[c * 8];
    float4 bv1 = *(const float4*)&b[c * 8 + 4];
    float ga[8] = {gv0.x, gv0.y, gv0.z, gv0.w, gv1.x, gv1.y, gv1.z, gv1.w};
    float ba[8] = {bv0.x, bv0.y, bv0.z, bv0.w, bv1.x, bv1.y, bv1.z, bv1.w};
    u16x8 ob;
#pragma unroll
    for (int u = 0; u < 8; u++) ob[u] = f2b((y[u] - mu) * rstd * ga[u] + ba[u]);
    if (half == 0)
        *(u16x8*)&xb[(size_t)n * 256 + c * 8] = ob;
}

// ---------------------------------------------------------------------------
extern "C" void kernel_launch(void* const* d_in, const int* in_sizes, int n_in,
                              void* d_out, int out_size, void* d_ws, size_t ws_size,
                              hipStream_t stream) {
    const float* h      = (const float*)d_in[0];
    const float* efeat  = (const float*)d_in[1];
    const int*   src    = (const int*)d_in[2];
    const int*   dst    = (const int*)d_in[3];
    const float* enc_w  = (const float*)d_in[4];
    const float* enc_b  = (const float*)d_in[5];
    const float* eenc_w = (const float*)d_in[6];
    const float* eenc_b = (const float*)d_in[7];
    const float* Wn     = (const float*)d_in[8];
    const float* We     = (const float*)d_in[9];
    const float* al     = (const float*)d_in[10];
    const float* ar     = (const float*)d_in[11];
    const float* ae     = (const float*)d_in[12];
    const float* ln_g   = (const float*)d_in[13];
    const float* ln_b   = (const float*)d_in[14];
    const float* out_w  = (const float*)d_in[15];
    const float* out_b  = (const float*)d_in[16];

    const int N = in_sizes[0] / 128;  // 50000
    const int E = in_sizes[2];        // 800000
    const int Mpad = ((N + 127) / 128) * 128;
    const int NB = (N + 1023) / 1024;

    char* ws = (char*)d_ws;
    size_t off = 0;
    auto alloc = [&](size_t bytes) -> char* {
        char* p = ws + off;
        off += (bytes + 255) & ~(size_t)255;
        return p;
    };
    ushort* Xb     = (ushort*)alloc((size_t)Mpad * 256 * 2);
    ushort* F      = (ushort*)alloc((size_t)Mpad * 256 * 2);
    ushort* hb     = (ushort*)alloc((size_t)Mpad * 128 * 2);
    float*  el     = (float*)alloc((size_t)N * 4 * 4);
    float*  er     = (float*)alloc((size_t)N * 4 * 4);
    ushort* ee_l   = (ushort*)alloc((size_t)E * 12 * 2);  // [3][E][4] bf16 CSR
    int*    esrc   = (int*)alloc((size_t)E * 4);
    int*    eid    = (int*)alloc((size_t)E * 4);
    int*    deg    = (int*)alloc((size_t)N * 4);
    int*    rowp   = (int*)alloc((size_t)(N + 1) * 4);
    int*    cursor = (int*)alloc((size_t)N * 4);
    int*    bsum   = (int*)alloc(64 * 4);
    int*    boff   = (int*)alloc(64 * 4);
    float*  ew     = (float*)alloc(3072 * 4);
    float*  eew2   = (float*)alloc(768 * 4);
    float*  eeb    = (float*)alloc(64);
    ushort* encT   = (ushort*)alloc(256 * 128 * 2);
    ushort* WnT    = (ushort*)alloc(3 * 256 * 256 * 2);
    ushort* outT   = (ushort*)alloc(256 * 256 * 2);
    (void)ws_size; (void)n_in; (void)out_size;

    // CSR by dst
    hipMemsetAsync(deg, 0, (size_t)N * 4, stream);
    k_deg<<<(E + 255) / 256, 256, 0, stream>>>(dst, deg, E);
    k_bsum<<<NB, 256, 0, stream>>>(deg, bsum, N);
    k_bscan<<<1, 64, 0, stream>>>(bsum, boff, rowp, NB, N);
    k_bwrite<<<NB, 256, 0, stream>>>(deg, boff, rowp, cursor, N);
    k_scatter<<<(E + 255) / 256, 256, 0, stream>>>(dst, src, cursor, eid, esrc, E);

    // prep (h->bf16, weight transposes, We*ae fold) then eew, then ee
    const int n4 = N * 128 / 4;
    k_prep<<<(n4 + 32768 + 4 * 65536 + 3072 + 255) / 256, 256, 0, stream>>>(
        h, enc_w, Wn, out_w, We, ae, hb, encT, WnT, outT, ew, n4);
    k_eew<<<4, 256, 0, stream>>>(eenc_w, eenc_b, ew, eew2, eeb);
    k_ee<<<(E + 127) / 128, 256, 0, stream>>>(efeat, eew2, eeb, eid, ee_l, E);

    dim3 gG(Mpad / 128, 2);
    // encoder: bf16 output only (residual lives in Xb)
    gemm_mfma<4, true, false, true, false><<<gG, 256, 0, stream>>>(
        hb, encT, enc_b, nullptr, Xb, nullptr, nullptr, nullptr, nullptr, N);

    for (int l = 0; l < 3; l++) {
        gemm_mfma<8, false, false, true, true><<<gG, 256, 0, stream>>>(
            Xb, WnT + (size_t)l * 65536, nullptr, nullptr, F,
            al + l * 256, ar + l * 256, el, er, N);
        k_agg<<<(N + 3) / 4, 256, 0, stream>>>(rowp, esrc, ee_l + (size_t)l * E * 4,
                                               el, er, F, Xb, ln_g + l * 256,
                                               ln_b + l * 256, N);
    }
    gemm_mfma<8, true, true, false, false><<<gG, 256, 0, stream>>>(
        Xb, outT, out_b, (float*)d_out, nullptr, nullptr, nullptr, nullptr, nullptr, N);
}